// Round 17
// baseline (1128.553 us; speedup 1.0000x reference)
//
#include <hip/hip_runtime.h>

#define EPS   1e-5f
#define SLOPE 0.01f

// ---------------------------------------------------------------------------
// conv 3x3x3 pad=1, ci-OUTER, S=1, COB=8, W4, fused BN-stat partials,
// LDS-tiled input (new vs R16): per ci, the block's 3x10x64 input rows are
// cooperatively staged into LDS (480 coalesced float4, ~4 loads/thread),
// then all 27 taps consume from LDS -- no global latency in the FMA phase,
// so kd/kh are fully unrolled (LDS reads don't trigger the R14 VGPR cliff).
// 64^3 layers only (block = 512 consecutive voxels = 8 W-rows of one slice).
// grid: (Cout/8, V/512), BT=128. bstat[c][blockIdx.y] = (sum,sumsq).
// ---------------------------------------------------------------------------
template <int CIN>
__global__ __launch_bounds__(128) void conv3_big(const float* __restrict__ in,
                                                 const float* __restrict__ wt,
                                                 float* __restrict__ out,
                                                 float* __restrict__ bstat) {
    const int V   = 64 * 64 * 64;
    const int NB  = gridDim.y;
    const int co0 = blockIdx.x * 8;
    __shared__ float wlds[27 * CIN * 8];
    __shared__ float tile[3][10][64];
    __shared__ float sred[2 * 16];
    for (int i = threadIdx.x; i < 27 * CIN * 8; i += 128) {
        const int co  = i & 7;
        const int r   = i >> 3;
        const int tap = r % 3;
        const int r2  = r / 3;
        const int pl  = r2 % 9;
        const int ci  = r2 / 9;
        wlds[i] = wt[((size_t)(co0 + co) * CIN + ci) * 27 + pl * 3 + tap];
    }

    const int vb    = blockIdx.y * 512;       // block-uniform
    const int d0    = vb >> 12;               // /4096
    const int hbase = (vb >> 6) & 63;
    const int hh0   = threadIdx.x >> 4;       // 0..7
    const int w0    = (threadIdx.x & 15) * 4; // 0..60
    const int v0    = vb + (hh0 * 64) + w0;   // == (blockIdx.y*128+tid)*4
    const bool mL = (w0 != 0);
    const bool mR = (w0 + 4 != 64);

    float acc[32];
#pragma unroll
    for (int i = 0; i < 32; ++i) acc[i] = 0.f;

#pragma unroll 1
    for (int ci = 0; ci < CIN; ++ci) {
        __syncthreads();   // tile consumers from previous ci done (also covers wlds on ci=0)
        const float* pc = in + (size_t)ci * V;
#pragma unroll
        for (int t = 0; t < 4; ++t) {                 // 480 float4 / 128 threads
            const int idx = threadIdx.x + t * 128;
            if (idx < 480) {
                const int r  = idx >> 4;              // 0..29
                const int wq = (idx & 15) * 4;
                const int kd = r / 10;
                const int hh = r - kd * 10;
                const int zd = d0 + kd - 1;
                const int zh = hbase + hh - 1;
                float4 val = make_float4(0.f, 0.f, 0.f, 0.f);
                if (((unsigned)zd < 64u) & ((unsigned)zh < 64u))
                    val = *(const float4*)(pc + ((zd << 6) + zh) * 64 + wq);
                *(float4*)&tile[kd][hh][wq] = val;
            }
        }
        __syncthreads();
#pragma unroll
        for (int kd = 0; kd < 3; ++kd) {
#pragma unroll
            for (int kh = 0; kh < 3; ++kh) {
                const float* trow = &tile[kd][hh0 + kh][0];
                const float4 m = *(const float4*)(trow + w0);
                const float lv = mL ? trow[w0 - 1] : 0.f;
                const float rv = mR ? trow[w0 + 4] : 0.f;
                const float* wb = &wlds[((ci * 9 + kd * 3 + kh) * 3) * 8];
                const float4 t0a = *(const float4*)(wb);        // tap0 co0..3
                const float4 t0b = *(const float4*)(wb + 4);    // tap0 co4..7
                const float4 t1a = *(const float4*)(wb + 8);
                const float4 t1b = *(const float4*)(wb + 12);
                const float4 t2a = *(const float4*)(wb + 16);
                const float4 t2b = *(const float4*)(wb + 20);
#define FMA4C(A0, A1, A2, AP)                                                       \
                {                                                                   \
                    float* a = (AP);                                                \
                    a[0] = fmaf(lv,  (A0), fmaf(m.x, (A1), fmaf(m.y, (A2), a[0]))); \
                    a[1] = fmaf(m.x, (A0), fmaf(m.y, (A1), fmaf(m.z, (A2), a[1]))); \
                    a[2] = fmaf(m.y, (A0), fmaf(m.z, (A1), fmaf(m.w, (A2), a[2]))); \
                    a[3] = fmaf(m.z, (A0), fmaf(m.w, (A1), fmaf(rv,  (A2), a[3]))); \
                }
                FMA4C(t0a.x, t1a.x, t2a.x, acc + 0);
                FMA4C(t0a.y, t1a.y, t2a.y, acc + 4);
                FMA4C(t0a.z, t1a.z, t2a.z, acc + 8);
                FMA4C(t0a.w, t1a.w, t2a.w, acc + 12);
                FMA4C(t0b.x, t1b.x, t2b.x, acc + 16);
                FMA4C(t0b.y, t1b.y, t2b.y, acc + 20);
                FMA4C(t0b.z, t1b.z, t2b.z, acc + 24);
                FMA4C(t0b.w, t1b.w, t2b.w, acc + 28);
#undef FMA4C
            }
        }
    }
#pragma unroll
    for (int co = 0; co < 8; ++co)
        *(float4*)&out[(size_t)(co0 + co) * V + v0] = *(const float4*)&acc[co * 4];

    // fused per-block BN stat partials (valid because S=1)
    float s1[8], s2[8];
#pragma unroll
    for (int co = 0; co < 8; ++co) {
        const float* a = &acc[co * 4];
        s1[co] = a[0] + a[1] + a[2] + a[3];
        s2[co] = fmaf(a[0], a[0], fmaf(a[1], a[1], fmaf(a[2], a[2], a[3] * a[3])));
    }
#pragma unroll
    for (int off = 32; off > 0; off >>= 1)
#pragma unroll
        for (int co = 0; co < 8; ++co) {
            s1[co] += __shfl_down(s1[co], off, 64);
            s2[co] += __shfl_down(s2[co], off, 64);
        }
    const int lane = threadIdx.x & 63;
    const int wv   = threadIdx.x >> 6;
    if (lane == 0)
#pragma unroll
        for (int co = 0; co < 8; ++co) {
            sred[(wv * 8 + co) * 2]     = s1[co];
            sred[(wv * 8 + co) * 2 + 1] = s2[co];
        }
    __syncthreads();
    if ((int)threadIdx.x < 8) {
        float S1 = 0.f, S2 = 0.f;
#pragma unroll
        for (int w = 0; w < 2; ++w) {
            S1 += sred[(w * 8 + threadIdx.x) * 2];
            S2 += sred[(w * 8 + threadIdx.x) * 2 + 1];
        }
        bstat[((size_t)(co0 + threadIdx.x) * NB + blockIdx.y) * 2]     = S1;
        bstat[((size_t)(co0 + threadIdx.x) * NB + blockIdx.y) * 2 + 1] = S2;
    }
}

// ---------------------------------------------------------------------------
// upconv, S=1, COB=8, VOXB=4, fused BN-stat partials (for up3). R11-proven.
// ---------------------------------------------------------------------------
template <int CIN>
__global__ __launch_bounds__(256) void upconv_big(const float* __restrict__ in,
                                                  const float* __restrict__ wt,
                                                  float* __restrict__ out,
                                                  float* __restrict__ bstat,
                                                  int Di, int Hi, int Wi) {
    const int Do = 2 * Di, Ho = 2 * Hi, Wo = 2 * Wi;
    const int Vo = Do * Ho * Wo;
    const int Vi = Di * Hi * Wi;
    const int NB = gridDim.y;
    const int co0 = blockIdx.x * 8;
    __shared__ float wlds[8 * CIN * 8];
    __shared__ float sred[4 * 16];
    for (int i = threadIdx.x; i < 8 * CIN * 8; i += 256) {
        const int co  = i & 7;
        const int t2  = i >> 3;
        const int ci  = t2 % CIN;
        const int tap = t2 / CIN;
        wlds[i] = wt[((size_t)(co0 + co) * CIN + ci) * 8 + tap];
    }
    __syncthreads();

    const int vbase = blockIdx.y * 1024 + threadIdx.x;
    int od[4], oh[4], ow[4];
#pragma unroll
    for (int j = 0; j < 4; ++j) {
        const int v = vbase + j * 256;
        ow[j] = v % Wo;
        oh[j] = (v / Wo) % Ho;
        od[j] = v / (Wo * Ho);
    }
    float acc[32];
#pragma unroll
    for (int i = 0; i < 32; ++i) acc[i] = 0.f;

#pragma unroll 1
    for (int kd = 0; kd < 2; ++kd)
#pragma unroll 1
    for (int kh = 0; kh < 2; ++kh)
#pragma unroll
    for (int kw = 0; kw < 2; ++kw) {
        const int tap = (kd * 2 + kh) * 2 + kw;
        int sp[4];
#pragma unroll
        for (int j = 0; j < 4; ++j) {
            const int id = ((od[j] - kd + Do) & (Do - 1)) >> 1;
            const int ih = ((oh[j] - kh + Ho) & (Ho - 1)) >> 1;
            const int iw = ((ow[j] - kw + Wo) & (Wo - 1)) >> 1;
            sp[j] = (id * Hi + ih) * Wi + iw;
        }
        const float* wrow = &wlds[tap * CIN * 8];
#pragma unroll 2
        for (int ci = 0; ci < CIN; ++ci) {
            float xv[4];
#pragma unroll
            for (int j = 0; j < 4; ++j)
                xv[j] = in[(size_t)ci * Vi + sp[j]];
            const float4 wa = *(const float4*)(wrow + ci * 8);
            const float4 wb = *(const float4*)(wrow + ci * 8 + 4);
#define UF(WC, CO)                                                              \
            {                                                                   \
                _Pragma("unroll")                                               \
                for (int j = 0; j < 4; ++j)                                     \
                    acc[(CO) * 4 + j] = fmaf(xv[j], (WC), acc[(CO) * 4 + j]);   \
            }
            UF(wa.x, 0) UF(wa.y, 1) UF(wa.z, 2) UF(wa.w, 3)
            UF(wb.x, 4) UF(wb.y, 5) UF(wb.z, 6) UF(wb.w, 7)
#undef UF
        }
    }
#pragma unroll
    for (int co = 0; co < 8; ++co)
#pragma unroll
        for (int j = 0; j < 4; ++j)
            out[(size_t)(co0 + co) * Vo + vbase + j * 256] = acc[co * 4 + j];

    float s1[8], s2[8];
#pragma unroll
    for (int co = 0; co < 8; ++co) {
        const float* a = &acc[co * 4];
        s1[co] = a[0] + a[1] + a[2] + a[3];
        s2[co] = fmaf(a[0], a[0], fmaf(a[1], a[1], fmaf(a[2], a[2], a[3] * a[3])));
    }
#pragma unroll
    for (int off = 32; off > 0; off >>= 1)
#pragma unroll
        for (int co = 0; co < 8; ++co) {
            s1[co] += __shfl_down(s1[co], off, 64);
            s2[co] += __shfl_down(s2[co], off, 64);
        }
    const int lane = threadIdx.x & 63;
    const int wv   = threadIdx.x >> 6;
    if (lane == 0)
#pragma unroll
        for (int co = 0; co < 8; ++co) {
            sred[(wv * 8 + co) * 2]     = s1[co];
            sred[(wv * 8 + co) * 2 + 1] = s2[co];
        }
    __syncthreads();
    if ((int)threadIdx.x < 8) {
        float S1 = 0.f, S2 = 0.f;
#pragma unroll
        for (int w = 0; w < 4; ++w) {
            S1 += sred[(w * 8 + threadIdx.x) * 2];
            S2 += sred[(w * 8 + threadIdx.x) * 2 + 1];
        }
        bstat[((size_t)(co0 + threadIdx.x) * NB + blockIdx.y) * 2]     = S1;
        bstat[((size_t)(co0 + threadIdx.x) * NB + blockIdx.y) * 2 + 1] = S2;
    }
}

// ---------------------------------------------------------------------------
// fused BN apply (bstat path): re-reduce per-block partials, normalize+lrelu.
// ---------------------------------------------------------------------------
__global__ __launch_bounds__(256) void bn_apply_f(const float* __restrict__ prt,
                                                  float* __restrict__ dst,
                                                  const float* __restrict__ bstat,
                                                  int NB, int V4, float invV) {
    const int c = blockIdx.x;
    float s1 = 0.f, s2 = 0.f;
    for (int i = threadIdx.x; i < NB; i += 256) {
        s1 += bstat[((size_t)c * NB + i) * 2];
        s2 += bstat[((size_t)c * NB + i) * 2 + 1];
    }
#pragma unroll
    for (int off = 32; off > 0; off >>= 1) {
        s1 += __shfl_down(s1, off, 64);
        s2 += __shfl_down(s2, off, 64);
    }
    __shared__ float sh[8];
    __shared__ float mv[2];
    const int lane = threadIdx.x & 63;
    const int wv   = threadIdx.x >> 6;
    if (lane == 0) { sh[wv] = s1; sh[4 + wv] = s2; }
    __syncthreads();
    if (threadIdx.x == 0) {
        const float S1 = sh[0] + sh[1] + sh[2] + sh[3];
        const float S2 = sh[4] + sh[5] + sh[6] + sh[7];
        const float mean = S1 * invV;
        const float var  = S2 * invV - mean * mean;
        mv[0] = mean;
        mv[1] = rsqrtf(var + EPS);
    }
    __syncthreads();
    const float mean = mv[0];
    const float rstd = mv[1];
    const int pos = blockIdx.y * 256 + threadIdx.x;
    float4 t = ((const float4*)prt)[(size_t)c * V4 + pos];
    float u;
    u = (t.x - mean) * rstd; t.x = u >= 0.f ? u : SLOPE * u;
    u = (t.y - mean) * rstd; t.y = u >= 0.f ? u : SLOPE * u;
    u = (t.z - mean) * rstd; t.z = u >= 0.f ? u : SLOPE * u;
    u = (t.w - mean) * rstd; t.w = u >= 0.f ? u : SLOPE * u;
    ((float4*)dst)[(size_t)c * V4 + pos] = t;
}

// ---------------------------------------------------------------------------
// conv 3x3x3 (R10-proven, 4-wide, ci-split): for 32^3 / 16^3 / 8^3 layers.
// ---------------------------------------------------------------------------
template <int CIN, int CC, int BT>
__global__ __launch_bounds__(BT) void conv3_qA(const float* __restrict__ in,
                                               const float* __restrict__ wt,
                                               float* __restrict__ part,
                                               int D, int H, int W) {
    const int V    = D * H * W;
    const int Cout = gridDim.x * 8;
    const int z    = blockIdx.z;
    const int cib  = z * CC;
    __shared__ float wlds[27 * CC * 8];
    const int co0 = blockIdx.x * 8;
    for (int i = threadIdx.x; i < 27 * CC * 8; i += BT) {
        const int co  = i & 7;
        const int t2  = i >> 3;
        const int tap = t2 % 3;
        const int t3  = t2 / 3;
        const int ci  = t3 % CC;
        const int pl  = t3 / CC;
        wlds[i] = wt[((size_t)(co0 + co) * CIN + cib + ci) * 27 + pl * 3 + tap];
    }
    __syncthreads();

    const float* inz = in + (size_t)cib * V;
    const int v0 = (blockIdx.y * BT + threadIdx.x) * 4;
    const int w0 = v0 % W;
    const int h0 = (v0 / W) % H;
    const int d0 = v0 / (W * H);

    const bool mL = (w0 != 0);
    const bool mR = (w0 + 4 != W);
    const int  wl = w0 - (mL ? 1 : 0);
    const int  wr = w0 + (mR ? 4 : 3);

    float acc[32];
#pragma unroll
    for (int i = 0; i < 32; ++i) acc[i] = 0.f;

#pragma unroll 1
    for (int kd = 0; kd < 3; ++kd) {
#pragma unroll 1
        for (int kh = 0; kh < 3; ++kh) {
            const int zd = d0 + kd - 1, zh = h0 + kh - 1;
            const bool okp = ((unsigned)zd < (unsigned)D) & ((unsigned)zh < (unsigned)H);
            const int row = okp ? (zd * H + zh) * W : 0;
            const float* wpl = &wlds[(kd * 3 + kh) * CC * 24];
#pragma unroll 2
            for (int ci = 0; ci < CC; ++ci) {
                const float* p = inz + (size_t)ci * V + row;
                float4 m = *(const float4*)(p + w0);
                float lv = p[wl];
                float rv = p[wr];
                if (!okp) { m.x = 0.f; m.y = 0.f; m.z = 0.f; m.w = 0.f; }
                if (!(okp && mL)) lv = 0.f;
                if (!(okp && mR)) rv = 0.f;
                const float* wb = wpl + ci * 24;
                const float4 t0a = *(const float4*)(wb);
                const float4 t0b = *(const float4*)(wb + 4);
                const float4 t1a = *(const float4*)(wb + 8);
                const float4 t1b = *(const float4*)(wb + 12);
                const float4 t2a = *(const float4*)(wb + 16);
                const float4 t2b = *(const float4*)(wb + 20);
#define FMA4C(A0, A1, A2, AP)                                                       \
                {                                                                   \
                    float* a = (AP);                                                \
                    a[0] = fmaf(lv,  (A0), fmaf(m.x, (A1), fmaf(m.y, (A2), a[0]))); \
                    a[1] = fmaf(m.x, (A0), fmaf(m.y, (A1), fmaf(m.z, (A2), a[1]))); \
                    a[2] = fmaf(m.y, (A0), fmaf(m.z, (A1), fmaf(m.w, (A2), a[2]))); \
                    a[3] = fmaf(m.z, (A0), fmaf(m.w, (A1), fmaf(rv,  (A2), a[3]))); \
                }
                FMA4C(t0a.x, t1a.x, t2a.x, acc + 0);
                FMA4C(t0a.y, t1a.y, t2a.y, acc + 4);
                FMA4C(t0a.z, t1a.z, t2a.z, acc + 8);
                FMA4C(t0a.w, t1a.w, t2a.w, acc + 12);
                FMA4C(t0b.x, t1b.x, t2b.x, acc + 16);
                FMA4C(t0b.y, t1b.y, t2b.y, acc + 20);
                FMA4C(t0b.z, t1b.z, t2b.z, acc + 24);
                FMA4C(t0b.w, t1b.w, t2b.w, acc + 28);
#undef FMA4C
            }
        }
    }
#pragma unroll
    for (int co = 0; co < 8; ++co)
        *(float4*)&part[((size_t)z * Cout + co0 + co) * V + v0] = *(const float4*)&acc[co * 4];
}

// ---------------------------------------------------------------------------
// upconv (R10-proven, ci-split) for up1/up2
// ---------------------------------------------------------------------------
template <int CIN, int CC, int VOXB>
__global__ __launch_bounds__(256) void upconv_v8(const float* __restrict__ in,
                                                 const float* __restrict__ wt,
                                                 float* __restrict__ part,
                                                 int Di, int Hi, int Wi) {
    const int Do = 2 * Di, Ho = 2 * Hi, Wo = 2 * Wi;
    const int Vo = Do * Ho * Wo;
    const int Vi = Di * Hi * Wi;
    const int Cout = gridDim.x * 8;
    const int z    = blockIdx.z;
    const int cib  = z * CC;
    __shared__ float wlds[8 * CC * 8];
    const int co0 = blockIdx.x * 8;
    for (int i = threadIdx.x; i < 8 * CC * 8; i += 256) {
        const int co  = i & 7;
        const int t2  = i >> 3;
        const int ci  = t2 % CC;
        const int tap = t2 / CC;
        wlds[i] = wt[((size_t)(co0 + co) * CIN + cib + ci) * 8 + tap];
    }
    __syncthreads();

    const float* inz = in + (size_t)cib * Vi;
    const int vbase = blockIdx.y * (256 * VOXB) + threadIdx.x;
    int od[VOXB], oh[VOXB], ow[VOXB];
#pragma unroll
    for (int j = 0; j < VOXB; ++j) {
        const int v = vbase + j * 256;
        ow[j] = v % Wo;
        oh[j] = (v / Wo) % Ho;
        od[j] = v / (Wo * Ho);
    }
    float acc[8 * VOXB];
#pragma unroll
    for (int i = 0; i < 8 * VOXB; ++i) acc[i] = 0.f;

#pragma unroll 1
    for (int kd = 0; kd < 2; ++kd)
#pragma unroll 1
    for (int kh = 0; kh < 2; ++kh)
#pragma unroll
    for (int kw = 0; kw < 2; ++kw) {
        const int tap = (kd * 2 + kh) * 2 + kw;
        int sp[VOXB];
#pragma unroll
        for (int j = 0; j < VOXB; ++j) {
            const int id = ((od[j] - kd + Do) & (Do - 1)) >> 1;
            const int ih = ((oh[j] - kh + Ho) & (Ho - 1)) >> 1;
            const int iw = ((ow[j] - kw + Wo) & (Wo - 1)) >> 1;
            sp[j] = (id * Hi + ih) * Wi + iw;
        }
        const float* wrow = &wlds[tap * CC * 8];
#pragma unroll 2
        for (int ci = 0; ci < CC; ++ci) {
            float xv[VOXB];
#pragma unroll
            for (int j = 0; j < VOXB; ++j)
                xv[j] = inz[(size_t)ci * Vi + sp[j]];
            const float4 wa = *(const float4*)(wrow + ci * 8);
            const float4 wb = *(const float4*)(wrow + ci * 8 + 4);
#define UF(WC, CO)                                                              \
            {                                                                   \
                _Pragma("unroll")                                               \
                for (int j = 0; j < VOXB; ++j)                                  \
                    acc[(CO) * VOXB + j] = fmaf(xv[j], (WC), acc[(CO) * VOXB + j]); \
            }
            UF(wa.x, 0) UF(wa.y, 1) UF(wa.z, 2) UF(wa.w, 3)
            UF(wb.x, 4) UF(wb.y, 5) UF(wb.z, 6) UF(wb.w, 7)
#undef UF
        }
    }
#pragma unroll
    for (int co = 0; co < 8; ++co)
#pragma unroll
        for (int j = 0; j < VOXB; ++j)
            part[((size_t)z * Cout + co0 + co) * Vo + vbase + j * 256] = acc[co * VOXB + j];
}

// ---------------------------------------------------------------------------
// split-aware BN pipeline: stats partials + (final∘apply).
// ---------------------------------------------------------------------------
__global__ __launch_bounds__(256) void bn_stats_part_v2(const float* __restrict__ part,
                                                        float* __restrict__ pstat,
                                                        int C, int V, int S, int chunk) {
    const int c = blockIdx.x, seg = blockIdx.y;
    const size_t base = (size_t)c * V + (size_t)seg * chunk;
    float s1 = 0.f, s2 = 0.f;
    for (int i = threadIdx.x * 4; i < chunk; i += 1024) {
        float4 t = make_float4(0.f, 0.f, 0.f, 0.f);
        for (int s = 0; s < S; ++s) {
            const float4 v = *(const float4*)(part + (size_t)s * C * V + base + i);
            t.x += v.x; t.y += v.y; t.z += v.z; t.w += v.w;
        }
        s1 += t.x + t.y + t.z + t.w;
        s2 = fmaf(t.x, t.x, fmaf(t.y, t.y, fmaf(t.z, t.z, fmaf(t.w, t.w, s2))));
    }
#pragma unroll
    for (int off = 32; off > 0; off >>= 1) {
        s1 += __shfl_down(s1, off, 64);
        s2 += __shfl_down(s2, off, 64);
    }
    __shared__ float sh[8];
    const int wid  = threadIdx.x >> 6;
    const int lane = threadIdx.x & 63;
    if (lane == 0) { sh[wid] = s1; sh[4 + wid] = s2; }
    __syncthreads();
    if (threadIdx.x == 0) {
        pstat[(c * gridDim.y + seg) * 2]     = sh[0] + sh[1] + sh[2] + sh[3];
        pstat[(c * gridDim.y + seg) * 2 + 1] = sh[4] + sh[5] + sh[6] + sh[7];
    }
}

__global__ __launch_bounds__(256) void bn_apply_v4(const float* __restrict__ part,
                                                   float* __restrict__ dst,
                                                   const float* __restrict__ pstat,
                                                   int C, int V4, int S, int NSEG,
                                                   float invV, int total4) {
    const int idx = blockIdx.x * blockDim.x + threadIdx.x;
    if (idx >= total4) return;
    const int c = idx / V4;
    const int v = idx - c * V4;
    float s1 = 0.f, s2 = 0.f;
    for (int g = 0; g < NSEG; ++g) {
        s1 += pstat[(c * NSEG + g) * 2];
        s2 += pstat[(c * NSEG + g) * 2 + 1];
    }
    const float mean = s1 * invV;
    const float var  = s2 * invV - mean * mean;
    const float rstd = rsqrtf(var + EPS);
    const float4* p4 = (const float4*)part;
    float4 t = make_float4(0.f, 0.f, 0.f, 0.f);
    for (int s = 0; s < S; ++s) {
        const float4 x = p4[(size_t)(s * C + c) * V4 + v];
        t.x += x.x; t.y += x.y; t.z += x.z; t.w += x.w;
    }
    float u;
    u = (t.x - mean) * rstd; t.x = u >= 0.f ? u : SLOPE * u;
    u = (t.y - mean) * rstd; t.y = u >= 0.f ? u : SLOPE * u;
    u = (t.z - mean) * rstd; t.z = u >= 0.f ? u : SLOPE * u;
    u = (t.w - mean) * rstd; t.w = u >= 0.f ? u : SLOPE * u;
    ((float4*)dst)[idx] = t;
}

// ---------------------------------------------------------------------------
// 2x2x2 maxpool stride 2
// ---------------------------------------------------------------------------
__global__ __launch_bounds__(256) void maxpool_kernel(const float* __restrict__ in,
                                                      float* __restrict__ out,
                                                      int D, int H, int W, int total) {
    const int Do = D >> 1, Ho = H >> 1, Wo = W >> 1;
    const int Vo = Do * Ho * Wo;
    const int idx = blockIdx.x * blockDim.x + threadIdx.x;
    if (idx >= total) return;
    const int c  = idx / Vo;
    const int v  = idx - c * Vo;
    const int ow = v % Wo;
    const int oh = (v / Wo) % Ho;
    const int od = v / (Wo * Ho);
    const size_t HW = (size_t)H * W;
    const float* p = in + (size_t)c * D * HW + (size_t)(2 * od) * HW + (size_t)(2 * oh) * W + 2 * ow;
    float m = p[0];
    m = fmaxf(m, p[1]);
    m = fmaxf(m, p[W]);
    m = fmaxf(m, p[W + 1]);
    m = fmaxf(m, p[HW]);
    m = fmaxf(m, p[HW + 1]);
    m = fmaxf(m, p[HW + W]);
    m = fmaxf(m, p[HW + W + 1]);
    out[idx] = m;
}

// ---------------------------------------------------------------------------
// final 1x1x1 conv + bias, float4
// ---------------------------------------------------------------------------
__global__ __launch_bounds__(256) void final_v2(const float* __restrict__ in,
                                                const float* __restrict__ w,
                                                const float* __restrict__ b,
                                                float* __restrict__ out, int C, int V4) {
    const int idx = blockIdx.x * blockDim.x + threadIdx.x;
    if (idx >= V4) return;
    const float bb = b[0];
    float4 acc = make_float4(bb, bb, bb, bb);
    for (int c = 0; c < C; ++c) {
        const float4 v = ((const float4*)in)[(size_t)c * V4 + idx];
        const float wc = w[c];
        acc.x = fmaf(v.x, wc, acc.x);
        acc.y = fmaf(v.y, wc, acc.y);
        acc.z = fmaf(v.z, wc, acc.z);
        acc.w = fmaf(v.w, wc, acc.w);
    }
    ((float4*)out)[idx] = acc;
}

// ---------------------------------------------------------------------------

extern "C" void kernel_launch(void* const* d_in, const int* in_sizes, int n_in,
                              void* d_out, int out_size, void* d_ws, size_t ws_size,
                              hipStream_t stream) {
    const float* x      = (const float*)d_in[0];
    const float* wf1    = (const float*)d_in[1];
    const float* wf2    = (const float*)d_in[2];
    const float* wd1a   = (const float*)d_in[3];
    const float* wd1b   = (const float*)d_in[4];
    const float* wd2a   = (const float*)d_in[5];
    const float* wd2b   = (const float*)d_in[6];
    const float* wd3a   = (const float*)d_in[7];
    const float* wd3b   = (const float*)d_in[8];
    const float* wt1    = (const float*)d_in[9];
    const float* wu1a   = (const float*)d_in[10];
    const float* wu1b   = (const float*)d_in[11];
    const float* wt2    = (const float*)d_in[12];
    const float* wu2a   = (const float*)d_in[13];
    const float* wu2b   = (const float*)d_in[14];
    const float* wt3    = (const float*)d_in[15];
    const float* wu3a   = (const float*)d_in[16];
    const float* wu3b   = (const float*)d_in[17];
    const float* w_fin  = (const float*)d_in[18];
    const float* b_fin  = (const float*)d_in[19];
    float* out = (float*)d_out;

    const int V0 = 64 * 64 * 64;
    const int V1 = 32 * 32 * 32;
    const int V2 = 16 * 16 * 16;
    const int V3 = 8 * 8 * 8;

    float* ws    = (float*)d_ws;
    float* cat3  = ws;                         // 32 * V0
    float* cat2  = cat3 + (size_t)32 * V0;     // 64 * V1
    float* cat1  = cat2 + (size_t)64 * V1;     // 128 * V2
    float* x4    = cat1 + (size_t)128 * V2;    // 128 * V3
    float* tA    = x4   + (size_t)128 * V3;    // 16 * V0
    float* tB    = tA   + (size_t)16 * V0;     // 16 * V0
    float* part  = tB   + (size_t)16 * V0;     // 16 * V0
    float* pstat = part + (size_t)16 * V0;     // 4096
    float* bstat = pstat + 4096;               // 16*512*2 = 16384

    auto blocks = [](int n) { return (n + 255) / 256; };

    auto bn_lrelu = [&](const float* p, float* dstp, int C, int V, int S) {
        const int NSEG = (V >= V0) ? 16 : (V == V1) ? 8 : (V == V2) ? 2 : 1;
        hipLaunchKernelGGL(bn_stats_part_v2, dim3(C, NSEG), dim3(256), 0, stream,
                           p, pstat, C, V, S, V / NSEG);
        const int total4 = C * V / 4;
        hipLaunchKernelGGL(bn_apply_v4, dim3(blocks(total4)), dim3(256), 0, stream,
                           p, dstp, pstat, C, V / 4, S, NSEG, 1.f / V, total4);
    };
    auto maxpool = [&](const float* in, float* o, int C, int D, int H, int W) {
        const int total = C * (D / 2) * (H / 2) * (W / 2);
        hipLaunchKernelGGL(maxpool_kernel, dim3(blocks(total)), dim3(256), 0, stream,
                           in, o, D, H, W, total);
    };

    // big 64^3 conv (LDS-tiled), S=1, fused stats: conv + bn_apply_f only.
#define CONVBIG(CIN, in_, wt_, prt_, dst_, Cout)                                            \
    {                                                                                       \
        const int NBv = V0 / 512;                                                           \
        dim3 g((Cout) / 8, NBv);                                                            \
        hipLaunchKernelGGL((conv3_big<CIN>), g, dim3(128), 0, stream,                       \
                           in_, wt_, prt_, bstat);                                          \
        hipLaunchKernelGGL(bn_apply_f, dim3(Cout, V0 / 4 / 256), dim3(256), 0, stream,      \
                           prt_, dst_, bstat, NBv, V0 / 4, 1.f / V0);                       \
    }
#define CONVQ(CIN, CC, BT, in_, wt_, prt_, dst_, Cout, D_, H_, W_)                          \
    {                                                                                       \
        const int V_ = (D_) * (H_) * (W_);                                                  \
        const int S  = (CIN) / (CC);                                                        \
        dim3 g((Cout) / 8, V_ / (4 * (BT)), S);                                             \
        hipLaunchKernelGGL((conv3_qA<CIN, CC, BT>), g, dim3(BT), 0, stream,                 \
                           in_, wt_, prt_, D_, H_, W_);                                     \
        bn_lrelu(prt_, dst_, Cout, V_, S);                                                  \
    }
#define UPCONV(CIN, CC, VOXB, in_, wt_, prt_, dst_, Cout, Di_, Hi_, Wi_)                    \
    {                                                                                       \
        const int Vo_ = 8 * (Di_) * (Hi_) * (Wi_);                                          \
        const int S  = (CIN) / (CC);                                                        \
        dim3 g((Cout) / 8, Vo_ / (256 * (VOXB)), S);                                        \
        hipLaunchKernelGGL((upconv_v8<CIN, CC, VOXB>), g, dim3(256), 0, stream,             \
                           in_, wt_, prt_, Di_, Hi_, Wi_);                                  \
        bn_lrelu(prt_, dst_, Cout, Vo_, S);                                                 \
    }

    // ----- encoder -----
    CONVBIG(1,  x,  wf1, tA, tA,   16);
    CONVBIG(16, tA, wf2, tB, cat3, 16);
    maxpool(cat3, tA, 16, 64, 64, 64);
    CONVQ(16,  8,  64,  tA,  wd1a, part, tB,          32, 32, 32, 32);
    CONVQ(32,  8,  64,  tB,  wd1b, part, cat2,        32, 32, 32, 32);
    maxpool(cat2, tA, 32, 32, 32, 32);
    CONVQ(32,  8,  64,  tA,  wd2a, part, tB,          64, 16, 16, 16);
    CONVQ(64,  8,  64,  tB,  wd2b, part, cat1,        64, 16, 16, 16);
    maxpool(cat1, tA, 64, 16, 16, 16);
    CONVQ(64,  4,  64,  tA,  wd3a, part, tB,         128, 8, 8, 8);
    CONVQ(128, 8,  64,  tB,  wd3b, part, x4,         128, 8, 8, 8);

    // ----- decoder -----
    UPCONV(128, 16, 1, x4, wt1, part, cat1 + (size_t)64 * V2, 64, 8, 8, 8);
    CONVQ(128, 8,  64, cat1, wu1a, part, tA,          64, 16, 16, 16);
    CONVQ(64,  8,  64, tA,   wu1b, part, tB,          64, 16, 16, 16);

    UPCONV(64, 16, 1, tB, wt2, part, cat2 + (size_t)32 * V1, 32, 16, 16, 16);
    CONVQ(64, 16, 64, cat2, wu2a, part, tA,           32, 32, 32, 32);
    CONVQ(32, 8,  64, tA,   wu2b, part, tB,           32, 32, 32, 32);

    {   // up3: S=1, fused stats, in-place apply into cat3[16:32]
        float* up3dst = cat3 + (size_t)16 * V0;
        const int NBv = V0 / 1024;
        dim3 g(2, NBv);
        hipLaunchKernelGGL((upconv_big<32>), g, dim3(256), 0, stream,
                           tB, wt3, up3dst, bstat, 32, 32, 32);
        hipLaunchKernelGGL(bn_apply_f, dim3(16, V0 / 4 / 256), dim3(256), 0, stream,
                           up3dst, up3dst, bstat, NBv, V0 / 4, 1.f / V0);
    }
    CONVBIG(32, cat3, wu3a, tB,   tA, 16);
    CONVBIG(16, tA,   wu3b, cat3, tB, 16);

    // ----- final 1x1x1 conv + bias -----
    hipLaunchKernelGGL(final_v2, dim3(blocks(V0 / 4)), dim3(256), 0, stream,
                       tB, w_fin, b_fin, out, 16, V0 / 4);

#undef CONVBIG
#undef CONVQ
#undef UPCONV
}

// Round 18
// 992.577 us; speedup vs baseline: 1.1370x; 1.1370x over previous
//
#include <hip/hip_runtime.h>

#define EPS   1e-5f
#define SLOPE 0.01f

// ---------------------------------------------------------------------------
// conv 3x3x3 pad=1, ci-OUTER, S=1, COB=8, W4, fused BN-stat partials,
// LDS-tiled input. R17 fixes: (1) tile padded to stride 68 (=4 mod 32 banks:
// each wave's 64 b128 reads spread uniformly, conflict-free -- R17's stride
// 64 gave 4-way conflicts, 1.5e7 SQ_LDS_BANK_CONFLICT); (2) consume kd loop
// pinned unroll 1 (R17's full kd x kh unroll -> VGPR 160, occupancy 11%).
// grid: (Cout/8, V/512), BT=128. bstat[c][blockIdx.y] = (sum,sumsq).
// ---------------------------------------------------------------------------
template <int CIN>
__global__ __launch_bounds__(128) void conv3_big(const float* __restrict__ in,
                                                 const float* __restrict__ wt,
                                                 float* __restrict__ out,
                                                 float* __restrict__ bstat) {
    const int V   = 64 * 64 * 64;
    const int NB  = gridDim.y;
    const int co0 = blockIdx.x * 8;
    __shared__ float wlds[27 * CIN * 8];
    __shared__ float tile[3][10][68];   // stride 68: bank-conflict-free
    __shared__ float sred[2 * 16];
    for (int i = threadIdx.x; i < 27 * CIN * 8; i += 128) {
        const int co  = i & 7;
        const int r   = i >> 3;
        const int tap = r % 3;
        const int r2  = r / 3;
        const int pl  = r2 % 9;
        const int ci  = r2 / 9;
        wlds[i] = wt[((size_t)(co0 + co) * CIN + ci) * 27 + pl * 3 + tap];
    }

    const int vb    = blockIdx.y * 512;       // block-uniform
    const int d0    = vb >> 12;               // /4096
    const int hbase = (vb >> 6) & 63;
    const int hh0   = threadIdx.x >> 4;       // 0..7
    const int w0    = (threadIdx.x & 15) * 4; // 0..60
    const int v0    = vb + (hh0 * 64) + w0;
    const bool mL = (w0 != 0);
    const bool mR = (w0 + 4 != 64);

    float acc[32];
#pragma unroll
    for (int i = 0; i < 32; ++i) acc[i] = 0.f;

#pragma unroll 1
    for (int ci = 0; ci < CIN; ++ci) {
        __syncthreads();   // prev-ci consumers done (covers wlds on ci=0)
        const float* pc = in + (size_t)ci * V;
#pragma unroll
        for (int t = 0; t < 4; ++t) {                 // 480 float4 / 128 threads
            const int idx = threadIdx.x + t * 128;
            if (idx < 480) {
                const int r  = idx >> 4;              // 0..29
                const int wq = (idx & 15) * 4;
                const int kd = r / 10;
                const int hh = r - kd * 10;
                const int zd = d0 + kd - 1;
                const int zh = hbase + hh - 1;
                float4 val = make_float4(0.f, 0.f, 0.f, 0.f);
                if (((unsigned)zd < 64u) & ((unsigned)zh < 64u))
                    val = *(const float4*)(pc + ((zd << 6) + zh) * 64 + wq);
                *(float4*)&tile[kd][hh][wq] = val;
            }
        }
        __syncthreads();
#pragma unroll 1
        for (int kd = 0; kd < 3; ++kd) {
#pragma unroll
            for (int kh = 0; kh < 3; ++kh) {
                const float* trow = &tile[kd][hh0 + kh][0];
                const float4 m = *(const float4*)(trow + w0);
                const float lv = mL ? trow[w0 - 1] : 0.f;
                const float rv = mR ? trow[w0 + 4] : 0.f;
                const float* wb = &wlds[((ci * 9 + kd * 3 + kh) * 3) * 8];
                const float4 t0a = *(const float4*)(wb);        // tap0 co0..3
                const float4 t0b = *(const float4*)(wb + 4);    // tap0 co4..7
                const float4 t1a = *(const float4*)(wb + 8);
                const float4 t1b = *(const float4*)(wb + 12);
                const float4 t2a = *(const float4*)(wb + 16);
                const float4 t2b = *(const float4*)(wb + 20);
#define FMA4C(A0, A1, A2, AP)                                                       \
                {                                                                   \
                    float* a = (AP);                                                \
                    a[0] = fmaf(lv,  (A0), fmaf(m.x, (A1), fmaf(m.y, (A2), a[0]))); \
                    a[1] = fmaf(m.x, (A0), fmaf(m.y, (A1), fmaf(m.z, (A2), a[1]))); \
                    a[2] = fmaf(m.y, (A0), fmaf(m.z, (A1), fmaf(m.w, (A2), a[2]))); \
                    a[3] = fmaf(m.z, (A0), fmaf(m.w, (A1), fmaf(rv,  (A2), a[3]))); \
                }
                FMA4C(t0a.x, t1a.x, t2a.x, acc + 0);
                FMA4C(t0a.y, t1a.y, t2a.y, acc + 4);
                FMA4C(t0a.z, t1a.z, t2a.z, acc + 8);
                FMA4C(t0a.w, t1a.w, t2a.w, acc + 12);
                FMA4C(t0b.x, t1b.x, t2b.x, acc + 16);
                FMA4C(t0b.y, t1b.y, t2b.y, acc + 20);
                FMA4C(t0b.z, t1b.z, t2b.z, acc + 24);
                FMA4C(t0b.w, t1b.w, t2b.w, acc + 28);
#undef FMA4C
            }
        }
    }
#pragma unroll
    for (int co = 0; co < 8; ++co)
        *(float4*)&out[(size_t)(co0 + co) * V + v0] = *(const float4*)&acc[co * 4];

    // fused per-block BN stat partials (valid because S=1)
    float s1[8], s2[8];
#pragma unroll
    for (int co = 0; co < 8; ++co) {
        const float* a = &acc[co * 4];
        s1[co] = a[0] + a[1] + a[2] + a[3];
        s2[co] = fmaf(a[0], a[0], fmaf(a[1], a[1], fmaf(a[2], a[2], a[3] * a[3])));
    }
#pragma unroll
    for (int off = 32; off > 0; off >>= 1)
#pragma unroll
        for (int co = 0; co < 8; ++co) {
            s1[co] += __shfl_down(s1[co], off, 64);
            s2[co] += __shfl_down(s2[co], off, 64);
        }
    const int lane = threadIdx.x & 63;
    const int wv   = threadIdx.x >> 6;
    if (lane == 0)
#pragma unroll
        for (int co = 0; co < 8; ++co) {
            sred[(wv * 8 + co) * 2]     = s1[co];
            sred[(wv * 8 + co) * 2 + 1] = s2[co];
        }
    __syncthreads();
    if ((int)threadIdx.x < 8) {
        float S1 = 0.f, S2 = 0.f;
#pragma unroll
        for (int w = 0; w < 2; ++w) {
            S1 += sred[(w * 8 + threadIdx.x) * 2];
            S2 += sred[(w * 8 + threadIdx.x) * 2 + 1];
        }
        bstat[((size_t)(co0 + threadIdx.x) * NB + blockIdx.y) * 2]     = S1;
        bstat[((size_t)(co0 + threadIdx.x) * NB + blockIdx.y) * 2 + 1] = S2;
    }
}

// ---------------------------------------------------------------------------
// upconv, S=1, COB=8, VOXB=4, fused BN-stat partials (for up3). R11-proven.
// ---------------------------------------------------------------------------
template <int CIN>
__global__ __launch_bounds__(256) void upconv_big(const float* __restrict__ in,
                                                  const float* __restrict__ wt,
                                                  float* __restrict__ out,
                                                  float* __restrict__ bstat,
                                                  int Di, int Hi, int Wi) {
    const int Do = 2 * Di, Ho = 2 * Hi, Wo = 2 * Wi;
    const int Vo = Do * Ho * Wo;
    const int Vi = Di * Hi * Wi;
    const int NB = gridDim.y;
    const int co0 = blockIdx.x * 8;
    __shared__ float wlds[8 * CIN * 8];
    __shared__ float sred[4 * 16];
    for (int i = threadIdx.x; i < 8 * CIN * 8; i += 256) {
        const int co  = i & 7;
        const int t2  = i >> 3;
        const int ci  = t2 % CIN;
        const int tap = t2 / CIN;
        wlds[i] = wt[((size_t)(co0 + co) * CIN + ci) * 8 + tap];
    }
    __syncthreads();

    const int vbase = blockIdx.y * 1024 + threadIdx.x;
    int od[4], oh[4], ow[4];
#pragma unroll
    for (int j = 0; j < 4; ++j) {
        const int v = vbase + j * 256;
        ow[j] = v % Wo;
        oh[j] = (v / Wo) % Ho;
        od[j] = v / (Wo * Ho);
    }
    float acc[32];
#pragma unroll
    for (int i = 0; i < 32; ++i) acc[i] = 0.f;

#pragma unroll 1
    for (int kd = 0; kd < 2; ++kd)
#pragma unroll 1
    for (int kh = 0; kh < 2; ++kh)
#pragma unroll
    for (int kw = 0; kw < 2; ++kw) {
        const int tap = (kd * 2 + kh) * 2 + kw;
        int sp[4];
#pragma unroll
        for (int j = 0; j < 4; ++j) {
            const int id = ((od[j] - kd + Do) & (Do - 1)) >> 1;
            const int ih = ((oh[j] - kh + Ho) & (Ho - 1)) >> 1;
            const int iw = ((ow[j] - kw + Wo) & (Wo - 1)) >> 1;
            sp[j] = (id * Hi + ih) * Wi + iw;
        }
        const float* wrow = &wlds[tap * CIN * 8];
#pragma unroll 2
        for (int ci = 0; ci < CIN; ++ci) {
            float xv[4];
#pragma unroll
            for (int j = 0; j < 4; ++j)
                xv[j] = in[(size_t)ci * Vi + sp[j]];
            const float4 wa = *(const float4*)(wrow + ci * 8);
            const float4 wb = *(const float4*)(wrow + ci * 8 + 4);
#define UF(WC, CO)                                                              \
            {                                                                   \
                _Pragma("unroll")                                               \
                for (int j = 0; j < 4; ++j)                                     \
                    acc[(CO) * 4 + j] = fmaf(xv[j], (WC), acc[(CO) * 4 + j]);   \
            }
            UF(wa.x, 0) UF(wa.y, 1) UF(wa.z, 2) UF(wa.w, 3)
            UF(wb.x, 4) UF(wb.y, 5) UF(wb.z, 6) UF(wb.w, 7)
#undef UF
        }
    }
#pragma unroll
    for (int co = 0; co < 8; ++co)
#pragma unroll
        for (int j = 0; j < 4; ++j)
            out[(size_t)(co0 + co) * Vo + vbase + j * 256] = acc[co * 4 + j];

    float s1[8], s2[8];
#pragma unroll
    for (int co = 0; co < 8; ++co) {
        const float* a = &acc[co * 4];
        s1[co] = a[0] + a[1] + a[2] + a[3];
        s2[co] = fmaf(a[0], a[0], fmaf(a[1], a[1], fmaf(a[2], a[2], a[3] * a[3])));
    }
#pragma unroll
    for (int off = 32; off > 0; off >>= 1)
#pragma unroll
        for (int co = 0; co < 8; ++co) {
            s1[co] += __shfl_down(s1[co], off, 64);
            s2[co] += __shfl_down(s2[co], off, 64);
        }
    const int lane = threadIdx.x & 63;
    const int wv   = threadIdx.x >> 6;
    if (lane == 0)
#pragma unroll
        for (int co = 0; co < 8; ++co) {
            sred[(wv * 8 + co) * 2]     = s1[co];
            sred[(wv * 8 + co) * 2 + 1] = s2[co];
        }
    __syncthreads();
    if ((int)threadIdx.x < 8) {
        float S1 = 0.f, S2 = 0.f;
#pragma unroll
        for (int w = 0; w < 4; ++w) {
            S1 += sred[(w * 8 + threadIdx.x) * 2];
            S2 += sred[(w * 8 + threadIdx.x) * 2 + 1];
        }
        bstat[((size_t)(co0 + threadIdx.x) * NB + blockIdx.y) * 2]     = S1;
        bstat[((size_t)(co0 + threadIdx.x) * NB + blockIdx.y) * 2 + 1] = S2;
    }
}

// ---------------------------------------------------------------------------
// fused BN apply (bstat path): re-reduce per-block partials, normalize+lrelu.
// ---------------------------------------------------------------------------
__global__ __launch_bounds__(256) void bn_apply_f(const float* __restrict__ prt,
                                                  float* __restrict__ dst,
                                                  const float* __restrict__ bstat,
                                                  int NB, int V4, float invV) {
    const int c = blockIdx.x;
    float s1 = 0.f, s2 = 0.f;
    for (int i = threadIdx.x; i < NB; i += 256) {
        s1 += bstat[((size_t)c * NB + i) * 2];
        s2 += bstat[((size_t)c * NB + i) * 2 + 1];
    }
#pragma unroll
    for (int off = 32; off > 0; off >>= 1) {
        s1 += __shfl_down(s1, off, 64);
        s2 += __shfl_down(s2, off, 64);
    }
    __shared__ float sh[8];
    __shared__ float mv[2];
    const int lane = threadIdx.x & 63;
    const int wv   = threadIdx.x >> 6;
    if (lane == 0) { sh[wv] = s1; sh[4 + wv] = s2; }
    __syncthreads();
    if (threadIdx.x == 0) {
        const float S1 = sh[0] + sh[1] + sh[2] + sh[3];
        const float S2 = sh[4] + sh[5] + sh[6] + sh[7];
        const float mean = S1 * invV;
        const float var  = S2 * invV - mean * mean;
        mv[0] = mean;
        mv[1] = rsqrtf(var + EPS);
    }
    __syncthreads();
    const float mean = mv[0];
    const float rstd = mv[1];
    const int pos = blockIdx.y * 256 + threadIdx.x;
    float4 t = ((const float4*)prt)[(size_t)c * V4 + pos];
    float u;
    u = (t.x - mean) * rstd; t.x = u >= 0.f ? u : SLOPE * u;
    u = (t.y - mean) * rstd; t.y = u >= 0.f ? u : SLOPE * u;
    u = (t.z - mean) * rstd; t.z = u >= 0.f ? u : SLOPE * u;
    u = (t.w - mean) * rstd; t.w = u >= 0.f ? u : SLOPE * u;
    ((float4*)dst)[(size_t)c * V4 + pos] = t;
}

// ---------------------------------------------------------------------------
// conv 3x3x3 (R10-proven, 4-wide, ci-split): for 32^3 / 16^3 / 8^3 layers.
// ---------------------------------------------------------------------------
template <int CIN, int CC, int BT>
__global__ __launch_bounds__(BT) void conv3_qA(const float* __restrict__ in,
                                               const float* __restrict__ wt,
                                               float* __restrict__ part,
                                               int D, int H, int W) {
    const int V    = D * H * W;
    const int Cout = gridDim.x * 8;
    const int z    = blockIdx.z;
    const int cib  = z * CC;
    __shared__ float wlds[27 * CC * 8];
    const int co0 = blockIdx.x * 8;
    for (int i = threadIdx.x; i < 27 * CC * 8; i += BT) {
        const int co  = i & 7;
        const int t2  = i >> 3;
        const int tap = t2 % 3;
        const int t3  = t2 / 3;
        const int ci  = t3 % CC;
        const int pl  = t3 / CC;
        wlds[i] = wt[((size_t)(co0 + co) * CIN + cib + ci) * 27 + pl * 3 + tap];
    }
    __syncthreads();

    const float* inz = in + (size_t)cib * V;
    const int v0 = (blockIdx.y * BT + threadIdx.x) * 4;
    const int w0 = v0 % W;
    const int h0 = (v0 / W) % H;
    const int d0 = v0 / (W * H);

    const bool mL = (w0 != 0);
    const bool mR = (w0 + 4 != W);
    const int  wl = w0 - (mL ? 1 : 0);
    const int  wr = w0 + (mR ? 4 : 3);

    float acc[32];
#pragma unroll
    for (int i = 0; i < 32; ++i) acc[i] = 0.f;

#pragma unroll 1
    for (int kd = 0; kd < 3; ++kd) {
#pragma unroll 1
        for (int kh = 0; kh < 3; ++kh) {
            const int zd = d0 + kd - 1, zh = h0 + kh - 1;
            const bool okp = ((unsigned)zd < (unsigned)D) & ((unsigned)zh < (unsigned)H);
            const int row = okp ? (zd * H + zh) * W : 0;
            const float* wpl = &wlds[(kd * 3 + kh) * CC * 24];
#pragma unroll 2
            for (int ci = 0; ci < CC; ++ci) {
                const float* p = inz + (size_t)ci * V + row;
                float4 m = *(const float4*)(p + w0);
                float lv = p[wl];
                float rv = p[wr];
                if (!okp) { m.x = 0.f; m.y = 0.f; m.z = 0.f; m.w = 0.f; }
                if (!(okp && mL)) lv = 0.f;
                if (!(okp && mR)) rv = 0.f;
                const float* wb = wpl + ci * 24;
                const float4 t0a = *(const float4*)(wb);
                const float4 t0b = *(const float4*)(wb + 4);
                const float4 t1a = *(const float4*)(wb + 8);
                const float4 t1b = *(const float4*)(wb + 12);
                const float4 t2a = *(const float4*)(wb + 16);
                const float4 t2b = *(const float4*)(wb + 20);
#define FMA4C(A0, A1, A2, AP)                                                       \
                {                                                                   \
                    float* a = (AP);                                                \
                    a[0] = fmaf(lv,  (A0), fmaf(m.x, (A1), fmaf(m.y, (A2), a[0]))); \
                    a[1] = fmaf(m.x, (A0), fmaf(m.y, (A1), fmaf(m.z, (A2), a[1]))); \
                    a[2] = fmaf(m.y, (A0), fmaf(m.z, (A1), fmaf(m.w, (A2), a[2]))); \
                    a[3] = fmaf(m.z, (A0), fmaf(m.w, (A1), fmaf(rv,  (A2), a[3]))); \
                }
                FMA4C(t0a.x, t1a.x, t2a.x, acc + 0);
                FMA4C(t0a.y, t1a.y, t2a.y, acc + 4);
                FMA4C(t0a.z, t1a.z, t2a.z, acc + 8);
                FMA4C(t0a.w, t1a.w, t2a.w, acc + 12);
                FMA4C(t0b.x, t1b.x, t2b.x, acc + 16);
                FMA4C(t0b.y, t1b.y, t2b.y, acc + 20);
                FMA4C(t0b.z, t1b.z, t2b.z, acc + 24);
                FMA4C(t0b.w, t1b.w, t2b.w, acc + 28);
#undef FMA4C
            }
        }
    }
#pragma unroll
    for (int co = 0; co < 8; ++co)
        *(float4*)&part[((size_t)z * Cout + co0 + co) * V + v0] = *(const float4*)&acc[co * 4];
}

// ---------------------------------------------------------------------------
// upconv (R10-proven, ci-split) for up1/up2
// ---------------------------------------------------------------------------
template <int CIN, int CC, int VOXB>
__global__ __launch_bounds__(256) void upconv_v8(const float* __restrict__ in,
                                                 const float* __restrict__ wt,
                                                 float* __restrict__ part,
                                                 int Di, int Hi, int Wi) {
    const int Do = 2 * Di, Ho = 2 * Hi, Wo = 2 * Wi;
    const int Vo = Do * Ho * Wo;
    const int Vi = Di * Hi * Wi;
    const int Cout = gridDim.x * 8;
    const int z    = blockIdx.z;
    const int cib  = z * CC;
    __shared__ float wlds[8 * CC * 8];
    const int co0 = blockIdx.x * 8;
    for (int i = threadIdx.x; i < 8 * CC * 8; i += 256) {
        const int co  = i & 7;
        const int t2  = i >> 3;
        const int ci  = t2 % CC;
        const int tap = t2 / CC;
        wlds[i] = wt[((size_t)(co0 + co) * CIN + cib + ci) * 8 + tap];
    }
    __syncthreads();

    const float* inz = in + (size_t)cib * Vi;
    const int vbase = blockIdx.y * (256 * VOXB) + threadIdx.x;
    int od[VOXB], oh[VOXB], ow[VOXB];
#pragma unroll
    for (int j = 0; j < VOXB; ++j) {
        const int v = vbase + j * 256;
        ow[j] = v % Wo;
        oh[j] = (v / Wo) % Ho;
        od[j] = v / (Wo * Ho);
    }
    float acc[8 * VOXB];
#pragma unroll
    for (int i = 0; i < 8 * VOXB; ++i) acc[i] = 0.f;

#pragma unroll 1
    for (int kd = 0; kd < 2; ++kd)
#pragma unroll 1
    for (int kh = 0; kh < 2; ++kh)
#pragma unroll
    for (int kw = 0; kw < 2; ++kw) {
        const int tap = (kd * 2 + kh) * 2 + kw;
        int sp[VOXB];
#pragma unroll
        for (int j = 0; j < VOXB; ++j) {
            const int id = ((od[j] - kd + Do) & (Do - 1)) >> 1;
            const int ih = ((oh[j] - kh + Ho) & (Ho - 1)) >> 1;
            const int iw = ((ow[j] - kw + Wo) & (Wo - 1)) >> 1;
            sp[j] = (id * Hi + ih) * Wi + iw;
        }
        const float* wrow = &wlds[tap * CC * 8];
#pragma unroll 2
        for (int ci = 0; ci < CC; ++ci) {
            float xv[VOXB];
#pragma unroll
            for (int j = 0; j < VOXB; ++j)
                xv[j] = inz[(size_t)ci * Vi + sp[j]];
            const float4 wa = *(const float4*)(wrow + ci * 8);
            const float4 wb = *(const float4*)(wrow + ci * 8 + 4);
#define UF(WC, CO)                                                              \
            {                                                                   \
                _Pragma("unroll")                                               \
                for (int j = 0; j < VOXB; ++j)                                  \
                    acc[(CO) * VOXB + j] = fmaf(xv[j], (WC), acc[(CO) * VOXB + j]); \
            }
            UF(wa.x, 0) UF(wa.y, 1) UF(wa.z, 2) UF(wa.w, 3)
            UF(wb.x, 4) UF(wb.y, 5) UF(wb.z, 6) UF(wb.w, 7)
#undef UF
        }
    }
#pragma unroll
    for (int co = 0; co < 8; ++co)
#pragma unroll
        for (int j = 0; j < VOXB; ++j)
            part[((size_t)z * Cout + co0 + co) * Vo + vbase + j * 256] = acc[co * VOXB + j];
}

// ---------------------------------------------------------------------------
// split-aware BN pipeline: stats partials + (final∘apply).
// ---------------------------------------------------------------------------
__global__ __launch_bounds__(256) void bn_stats_part_v2(const float* __restrict__ part,
                                                        float* __restrict__ pstat,
                                                        int C, int V, int S, int chunk) {
    const int c = blockIdx.x, seg = blockIdx.y;
    const size_t base = (size_t)c * V + (size_t)seg * chunk;
    float s1 = 0.f, s2 = 0.f;
    for (int i = threadIdx.x * 4; i < chunk; i += 1024) {
        float4 t = make_float4(0.f, 0.f, 0.f, 0.f);
        for (int s = 0; s < S; ++s) {
            const float4 v = *(const float4*)(part + (size_t)s * C * V + base + i);
            t.x += v.x; t.y += v.y; t.z += v.z; t.w += v.w;
        }
        s1 += t.x + t.y + t.z + t.w;
        s2 = fmaf(t.x, t.x, fmaf(t.y, t.y, fmaf(t.z, t.z, fmaf(t.w, t.w, s2))));
    }
#pragma unroll
    for (int off = 32; off > 0; off >>= 1) {
        s1 += __shfl_down(s1, off, 64);
        s2 += __shfl_down(s2, off, 64);
    }
    __shared__ float sh[8];
    const int wid  = threadIdx.x >> 6;
    const int lane = threadIdx.x & 63;
    if (lane == 0) { sh[wid] = s1; sh[4 + wid] = s2; }
    __syncthreads();
    if (threadIdx.x == 0) {
        pstat[(c * gridDim.y + seg) * 2]     = sh[0] + sh[1] + sh[2] + sh[3];
        pstat[(c * gridDim.y + seg) * 2 + 1] = sh[4] + sh[5] + sh[6] + sh[7];
    }
}

__global__ __launch_bounds__(256) void bn_apply_v4(const float* __restrict__ part,
                                                   float* __restrict__ dst,
                                                   const float* __restrict__ pstat,
                                                   int C, int V4, int S, int NSEG,
                                                   float invV, int total4) {
    const int idx = blockIdx.x * blockDim.x + threadIdx.x;
    if (idx >= total4) return;
    const int c = idx / V4;
    const int v = idx - c * V4;
    float s1 = 0.f, s2 = 0.f;
    for (int g = 0; g < NSEG; ++g) {
        s1 += pstat[(c * NSEG + g) * 2];
        s2 += pstat[(c * NSEG + g) * 2 + 1];
    }
    const float mean = s1 * invV;
    const float var  = s2 * invV - mean * mean;
    const float rstd = rsqrtf(var + EPS);
    const float4* p4 = (const float4*)part;
    float4 t = make_float4(0.f, 0.f, 0.f, 0.f);
    for (int s = 0; s < S; ++s) {
        const float4 x = p4[(size_t)(s * C + c) * V4 + v];
        t.x += x.x; t.y += x.y; t.z += x.z; t.w += x.w;
    }
    float u;
    u = (t.x - mean) * rstd; t.x = u >= 0.f ? u : SLOPE * u;
    u = (t.y - mean) * rstd; t.y = u >= 0.f ? u : SLOPE * u;
    u = (t.z - mean) * rstd; t.z = u >= 0.f ? u : SLOPE * u;
    u = (t.w - mean) * rstd; t.w = u >= 0.f ? u : SLOPE * u;
    ((float4*)dst)[idx] = t;
}

// ---------------------------------------------------------------------------
// 2x2x2 maxpool stride 2
// ---------------------------------------------------------------------------
__global__ __launch_bounds__(256) void maxpool_kernel(const float* __restrict__ in,
                                                      float* __restrict__ out,
                                                      int D, int H, int W, int total) {
    const int Do = D >> 1, Ho = H >> 1, Wo = W >> 1;
    const int Vo = Do * Ho * Wo;
    const int idx = blockIdx.x * blockDim.x + threadIdx.x;
    if (idx >= total) return;
    const int c  = idx / Vo;
    const int v  = idx - c * Vo;
    const int ow = v % Wo;
    const int oh = (v / Wo) % Ho;
    const int od = v / (Wo * Ho);
    const size_t HW = (size_t)H * W;
    const float* p = in + (size_t)c * D * HW + (size_t)(2 * od) * HW + (size_t)(2 * oh) * W + 2 * ow;
    float m = p[0];
    m = fmaxf(m, p[1]);
    m = fmaxf(m, p[W]);
    m = fmaxf(m, p[W + 1]);
    m = fmaxf(m, p[HW]);
    m = fmaxf(m, p[HW + 1]);
    m = fmaxf(m, p[HW + W]);
    m = fmaxf(m, p[HW + W + 1]);
    out[idx] = m;
}

// ---------------------------------------------------------------------------
// final 1x1x1 conv + bias, float4
// ---------------------------------------------------------------------------
__global__ __launch_bounds__(256) void final_v2(const float* __restrict__ in,
                                                const float* __restrict__ w,
                                                const float* __restrict__ b,
                                                float* __restrict__ out, int C, int V4) {
    const int idx = blockIdx.x * blockDim.x + threadIdx.x;
    if (idx >= V4) return;
    const float bb = b[0];
    float4 acc = make_float4(bb, bb, bb, bb);
    for (int c = 0; c < C; ++c) {
        const float4 v = ((const float4*)in)[(size_t)c * V4 + idx];
        const float wc = w[c];
        acc.x = fmaf(v.x, wc, acc.x);
        acc.y = fmaf(v.y, wc, acc.y);
        acc.z = fmaf(v.z, wc, acc.z);
        acc.w = fmaf(v.w, wc, acc.w);
    }
    ((float4*)out)[idx] = acc;
}

// ---------------------------------------------------------------------------

extern "C" void kernel_launch(void* const* d_in, const int* in_sizes, int n_in,
                              void* d_out, int out_size, void* d_ws, size_t ws_size,
                              hipStream_t stream) {
    const float* x      = (const float*)d_in[0];
    const float* wf1    = (const float*)d_in[1];
    const float* wf2    = (const float*)d_in[2];
    const float* wd1a   = (const float*)d_in[3];
    const float* wd1b   = (const float*)d_in[4];
    const float* wd2a   = (const float*)d_in[5];
    const float* wd2b   = (const float*)d_in[6];
    const float* wd3a   = (const float*)d_in[7];
    const float* wd3b   = (const float*)d_in[8];
    const float* wt1    = (const float*)d_in[9];
    const float* wu1a   = (const float*)d_in[10];
    const float* wu1b   = (const float*)d_in[11];
    const float* wt2    = (const float*)d_in[12];
    const float* wu2a   = (const float*)d_in[13];
    const float* wu2b   = (const float*)d_in[14];
    const float* wt3    = (const float*)d_in[15];
    const float* wu3a   = (const float*)d_in[16];
    const float* wu3b   = (const float*)d_in[17];
    const float* w_fin  = (const float*)d_in[18];
    const float* b_fin  = (const float*)d_in[19];
    float* out = (float*)d_out;

    const int V0 = 64 * 64 * 64;
    const int V1 = 32 * 32 * 32;
    const int V2 = 16 * 16 * 16;
    const int V3 = 8 * 8 * 8;

    float* ws    = (float*)d_ws;
    float* cat3  = ws;                         // 32 * V0
    float* cat2  = cat3 + (size_t)32 * V0;     // 64 * V1
    float* cat1  = cat2 + (size_t)64 * V1;     // 128 * V2
    float* x4    = cat1 + (size_t)128 * V2;    // 128 * V3
    float* tA    = x4   + (size_t)128 * V3;    // 16 * V0
    float* tB    = tA   + (size_t)16 * V0;     // 16 * V0
    float* part  = tB   + (size_t)16 * V0;     // 16 * V0
    float* pstat = part + (size_t)16 * V0;     // 4096
    float* bstat = pstat + 4096;               // 16*512*2 = 16384

    auto blocks = [](int n) { return (n + 255) / 256; };

    auto bn_lrelu = [&](const float* p, float* dstp, int C, int V, int S) {
        const int NSEG = (V >= V0) ? 16 : (V == V1) ? 8 : (V == V2) ? 2 : 1;
        hipLaunchKernelGGL(bn_stats_part_v2, dim3(C, NSEG), dim3(256), 0, stream,
                           p, pstat, C, V, S, V / NSEG);
        const int total4 = C * V / 4;
        hipLaunchKernelGGL(bn_apply_v4, dim3(blocks(total4)), dim3(256), 0, stream,
                           p, dstp, pstat, C, V / 4, S, NSEG, 1.f / V, total4);
    };
    auto maxpool = [&](const float* in, float* o, int C, int D, int H, int W) {
        const int total = C * (D / 2) * (H / 2) * (W / 2);
        hipLaunchKernelGGL(maxpool_kernel, dim3(blocks(total)), dim3(256), 0, stream,
                           in, o, D, H, W, total);
    };

    // big 64^3 conv (LDS-tiled, padded), S=1, fused stats.
#define CONVBIG(CIN, in_, wt_, prt_, dst_, Cout)                                            \
    {                                                                                       \
        const int NBv = V0 / 512;                                                           \
        dim3 g((Cout) / 8, NBv);                                                            \
        hipLaunchKernelGGL((conv3_big<CIN>), g, dim3(128), 0, stream,                       \
                           in_, wt_, prt_, bstat);                                          \
        hipLaunchKernelGGL(bn_apply_f, dim3(Cout, V0 / 4 / 256), dim3(256), 0, stream,      \
                           prt_, dst_, bstat, NBv, V0 / 4, 1.f / V0);                       \
    }
#define CONVQ(CIN, CC, BT, in_, wt_, prt_, dst_, Cout, D_, H_, W_)                          \
    {                                                                                       \
        const int V_ = (D_) * (H_) * (W_);                                                  \
        const int S  = (CIN) / (CC);                                                        \
        dim3 g((Cout) / 8, V_ / (4 * (BT)), S);                                             \
        hipLaunchKernelGGL((conv3_qA<CIN, CC, BT>), g, dim3(BT), 0, stream,                 \
                           in_, wt_, prt_, D_, H_, W_);                                     \
        bn_lrelu(prt_, dst_, Cout, V_, S);                                                  \
    }
#define UPCONV(CIN, CC, VOXB, in_, wt_, prt_, dst_, Cout, Di_, Hi_, Wi_)                    \
    {                                                                                       \
        const int Vo_ = 8 * (Di_) * (Hi_) * (Wi_);                                          \
        const int S  = (CIN) / (CC);                                                        \
        dim3 g((Cout) / 8, Vo_ / (256 * (VOXB)), S);                                        \
        hipLaunchKernelGGL((upconv_v8<CIN, CC, VOXB>), g, dim3(256), 0, stream,             \
                           in_, wt_, prt_, Di_, Hi_, Wi_);                                  \
        bn_lrelu(prt_, dst_, Cout, Vo_, S);                                                 \
    }

    // ----- encoder -----
    CONVBIG(1,  x,  wf1, tA, tA,   16);
    CONVBIG(16, tA, wf2, tB, cat3, 16);
    maxpool(cat3, tA, 16, 64, 64, 64);
    CONVQ(16,  8,  64,  tA,  wd1a, part, tB,          32, 32, 32, 32);
    CONVQ(32,  8,  64,  tB,  wd1b, part, cat2,        32, 32, 32, 32);
    maxpool(cat2, tA, 32, 32, 32, 32);
    CONVQ(32,  8,  64,  tA,  wd2a, part, tB,          64, 16, 16, 16);
    CONVQ(64,  8,  64,  tB,  wd2b, part, cat1,        64, 16, 16, 16);
    maxpool(cat1, tA, 64, 16, 16, 16);
    CONVQ(64,  4,  64,  tA,  wd3a, part, tB,         128, 8, 8, 8);
    CONVQ(128, 8,  64,  tB,  wd3b, part, x4,         128, 8, 8, 8);

    // ----- decoder -----
    UPCONV(128, 16, 1, x4, wt1, part, cat1 + (size_t)64 * V2, 64, 8, 8, 8);
    CONVQ(128, 8,  64, cat1, wu1a, part, tA,          64, 16, 16, 16);
    CONVQ(64,  8,  64, tA,   wu1b, part, tB,          64, 16, 16, 16);

    UPCONV(64, 16, 1, tB, wt2, part, cat2 + (size_t)32 * V1, 32, 16, 16, 16);
    CONVQ(64, 16, 64, cat2, wu2a, part, tA,           32, 32, 32, 32);
    CONVQ(32, 8,  64, tA,   wu2b, part, tB,           32, 32, 32, 32);

    {   // up3: S=1, fused stats, in-place apply into cat3[16:32]
        float* up3dst = cat3 + (size_t)16 * V0;
        const int NBv = V0 / 1024;
        dim3 g(2, NBv);
        hipLaunchKernelGGL((upconv_big<32>), g, dim3(256), 0, stream,
                           tB, wt3, up3dst, bstat, 32, 32, 32);
        hipLaunchKernelGGL(bn_apply_f, dim3(16, V0 / 4 / 256), dim3(256), 0, stream,
                           up3dst, up3dst, bstat, NBv, V0 / 4, 1.f / V0);
    }
    CONVBIG(32, cat3, wu3a, tB,   tA, 16);
    CONVBIG(16, tA,   wu3b, cat3, tB, 16);

    // ----- final 1x1x1 conv + bias -----
    hipLaunchKernelGGL(final_v2, dim3(blocks(V0 / 4)), dim3(256), 0, stream,
                       tB, w_fin, b_fin, out, 16, V0 / 4);

#undef CONVBIG
#undef CONVQ
#undef UPCONV
}

// Round 19
// 964.276 us; speedup vs baseline: 1.1704x; 1.0293x over previous
//
#include <hip/hip_runtime.h>

#define EPS   1e-5f
#define SLOPE 0.01f

// ---------------------------------------------------------------------------
// conv 3x3x3 pad=1, ci-OUTER, S=1, COB=8, W4, fused BN-stat partials,
// LDS-tiled input (R18-proven: pad 68, consume kd unroll 1) + NEW register
// prefetch pipeline: ci+1's 4 global float4 are loaded into registers during
// ci's consume phase (waitcnt lands before next LDS write -> ~1700cy cover),
// and staging address math is hoisted out of the ci loop (ci-invariant).
// grid: (Cout/8, V/512), BT=128. bstat[c][blockIdx.y] = (sum,sumsq).
// ---------------------------------------------------------------------------
template <int CIN>
__global__ __launch_bounds__(128) void conv3_big(const float* __restrict__ in,
                                                 const float* __restrict__ wt,
                                                 float* __restrict__ out,
                                                 float* __restrict__ bstat) {
    const int V   = 64 * 64 * 64;
    const int NB  = gridDim.y;
    const int co0 = blockIdx.x * 8;
    __shared__ float wlds[27 * CIN * 8];
    __shared__ float tile[3][10][68];   // stride 68: minimal bank aliasing
    __shared__ float sred[2 * 16];
    for (int i = threadIdx.x; i < 27 * CIN * 8; i += 128) {
        const int co  = i & 7;
        const int r   = i >> 3;
        const int tap = r % 3;
        const int r2  = r / 3;
        const int pl  = r2 % 9;
        const int ci  = r2 / 9;
        wlds[i] = wt[((size_t)(co0 + co) * CIN + ci) * 27 + pl * 3 + tap];
    }

    const int vb    = blockIdx.y * 512;       // block-uniform
    const int d0    = vb >> 12;               // /4096
    const int hbase = (vb >> 6) & 63;
    const int hh0   = threadIdx.x >> 4;       // 0..7
    const int w0    = (threadIdx.x & 15) * 4; // 0..60
    const int v0    = vb + (hh0 * 64) + w0;
    const bool mL = (w0 != 0);
    const bool mR = (w0 + 4 != 64);

    // ci-invariant staging decode (4 quads per thread; idx<480 valid)
    int  goff[4];   // global offset within channel (clamped safe)
    int  loff[4];   // LDS float-offset into tile
    bool gok[4];    // in-bounds (zd,zh)
    bool act[4];    // idx < 480
#pragma unroll
    for (int t = 0; t < 4; ++t) {
        const int idx = threadIdx.x + t * 128;
        act[t] = (idx < 480);
        const int r  = idx >> 4;              // 0..29
        const int wq = (idx & 15) * 4;
        const int kd = r / 10;
        const int hh = r - kd * 10;
        const int zd = d0 + kd - 1;
        const int zh = hbase + hh - 1;
        gok[t]  = act[t] & ((unsigned)zd < 64u) & ((unsigned)zh < 64u);
        goff[t] = gok[t] ? ((zd << 6) + zh) * 64 + wq : 0;
        loff[t] = (kd * 10 + hh) * 68 + wq;
    }

    float acc[32];
#pragma unroll
    for (int i = 0; i < 32; ++i) acc[i] = 0.f;

    // prologue: prefetch ci=0
    float4 pre[4];
    {
        const float* pc = in;
#pragma unroll
        for (int t = 0; t < 4; ++t) {
            float4 val = make_float4(0.f, 0.f, 0.f, 0.f);
            if (gok[t]) val = *(const float4*)(pc + goff[t]);
            pre[t] = val;
        }
    }

#pragma unroll 1
    for (int ci = 0; ci < CIN; ++ci) {
        __syncthreads();   // prev-ci consumers done (covers wlds on ci=0)
#pragma unroll
        for (int t = 0; t < 4; ++t)
            if (act[t]) *(float4*)&((float*)tile)[loff[t]] = pre[t];
        // issue ci+1 loads now; latency hidden under the consume phase below
        if (ci + 1 < CIN) {
            const float* pc = in + (size_t)(ci + 1) * V;
#pragma unroll
            for (int t = 0; t < 4; ++t) {
                float4 val = make_float4(0.f, 0.f, 0.f, 0.f);
                if (gok[t]) val = *(const float4*)(pc + goff[t]);
                pre[t] = val;
            }
        }
        __syncthreads();   // tile ready
#pragma unroll 1
        for (int kd = 0; kd < 3; ++kd) {
#pragma unroll
            for (int kh = 0; kh < 3; ++kh) {
                const float* trow = &tile[kd][hh0 + kh][0];
                const float4 m = *(const float4*)(trow + w0);
                const float lv = mL ? trow[w0 - 1] : 0.f;
                const float rv = mR ? trow[w0 + 4] : 0.f;
                const float* wb = &wlds[((ci * 9 + kd * 3 + kh) * 3) * 8];
                const float4 t0a = *(const float4*)(wb);        // tap0 co0..3
                const float4 t0b = *(const float4*)(wb + 4);    // tap0 co4..7
                const float4 t1a = *(const float4*)(wb + 8);
                const float4 t1b = *(const float4*)(wb + 12);
                const float4 t2a = *(const float4*)(wb + 16);
                const float4 t2b = *(const float4*)(wb + 20);
#define FMA4C(A0, A1, A2, AP)                                                       \
                {                                                                   \
                    float* a = (AP);                                                \
                    a[0] = fmaf(lv,  (A0), fmaf(m.x, (A1), fmaf(m.y, (A2), a[0]))); \
                    a[1] = fmaf(m.x, (A0), fmaf(m.y, (A1), fmaf(m.z, (A2), a[1]))); \
                    a[2] = fmaf(m.y, (A0), fmaf(m.z, (A1), fmaf(m.w, (A2), a[2]))); \
                    a[3] = fmaf(m.z, (A0), fmaf(m.w, (A1), fmaf(rv,  (A2), a[3]))); \
                }
                FMA4C(t0a.x, t1a.x, t2a.x, acc + 0);
                FMA4C(t0a.y, t1a.y, t2a.y, acc + 4);
                FMA4C(t0a.z, t1a.z, t2a.z, acc + 8);
                FMA4C(t0a.w, t1a.w, t2a.w, acc + 12);
                FMA4C(t0b.x, t1b.x, t2b.x, acc + 16);
                FMA4C(t0b.y, t1b.y, t2b.y, acc + 20);
                FMA4C(t0b.z, t1b.z, t2b.z, acc + 24);
                FMA4C(t0b.w, t1b.w, t2b.w, acc + 28);
#undef FMA4C
            }
        }
    }
#pragma unroll
    for (int co = 0; co < 8; ++co)
        *(float4*)&out[(size_t)(co0 + co) * V + v0] = *(const float4*)&acc[co * 4];

    // fused per-block BN stat partials (valid because S=1)
    float s1[8], s2[8];
#pragma unroll
    for (int co = 0; co < 8; ++co) {
        const float* a = &acc[co * 4];
        s1[co] = a[0] + a[1] + a[2] + a[3];
        s2[co] = fmaf(a[0], a[0], fmaf(a[1], a[1], fmaf(a[2], a[2], a[3] * a[3])));
    }
#pragma unroll
    for (int off = 32; off > 0; off >>= 1)
#pragma unroll
        for (int co = 0; co < 8; ++co) {
            s1[co] += __shfl_down(s1[co], off, 64);
            s2[co] += __shfl_down(s2[co], off, 64);
        }
    const int lane = threadIdx.x & 63;
    const int wv   = threadIdx.x >> 6;
    if (lane == 0)
#pragma unroll
        for (int co = 0; co < 8; ++co) {
            sred[(wv * 8 + co) * 2]     = s1[co];
            sred[(wv * 8 + co) * 2 + 1] = s2[co];
        }
    __syncthreads();
    if ((int)threadIdx.x < 8) {
        float S1 = 0.f, S2 = 0.f;
#pragma unroll
        for (int w = 0; w < 2; ++w) {
            S1 += sred[(w * 8 + threadIdx.x) * 2];
            S2 += sred[(w * 8 + threadIdx.x) * 2 + 1];
        }
        bstat[((size_t)(co0 + threadIdx.x) * NB + blockIdx.y) * 2]     = S1;
        bstat[((size_t)(co0 + threadIdx.x) * NB + blockIdx.y) * 2 + 1] = S2;
    }
}

// ---------------------------------------------------------------------------
// upconv, S=1, COB=8, VOXB=4, fused BN-stat partials (for up3). R11-proven.
// ---------------------------------------------------------------------------
template <int CIN>
__global__ __launch_bounds__(256) void upconv_big(const float* __restrict__ in,
                                                  const float* __restrict__ wt,
                                                  float* __restrict__ out,
                                                  float* __restrict__ bstat,
                                                  int Di, int Hi, int Wi) {
    const int Do = 2 * Di, Ho = 2 * Hi, Wo = 2 * Wi;
    const int Vo = Do * Ho * Wo;
    const int Vi = Di * Hi * Wi;
    const int NB = gridDim.y;
    const int co0 = blockIdx.x * 8;
    __shared__ float wlds[8 * CIN * 8];
    __shared__ float sred[4 * 16];
    for (int i = threadIdx.x; i < 8 * CIN * 8; i += 256) {
        const int co  = i & 7;
        const int t2  = i >> 3;
        const int ci  = t2 % CIN;
        const int tap = t2 / CIN;
        wlds[i] = wt[((size_t)(co0 + co) * CIN + ci) * 8 + tap];
    }
    __syncthreads();

    const int vbase = blockIdx.y * 1024 + threadIdx.x;
    int od[4], oh[4], ow[4];
#pragma unroll
    for (int j = 0; j < 4; ++j) {
        const int v = vbase + j * 256;
        ow[j] = v % Wo;
        oh[j] = (v / Wo) % Ho;
        od[j] = v / (Wo * Ho);
    }
    float acc[32];
#pragma unroll
    for (int i = 0; i < 32; ++i) acc[i] = 0.f;

#pragma unroll 1
    for (int kd = 0; kd < 2; ++kd)
#pragma unroll 1
    for (int kh = 0; kh < 2; ++kh)
#pragma unroll
    for (int kw = 0; kw < 2; ++kw) {
        const int tap = (kd * 2 + kh) * 2 + kw;
        int sp[4];
#pragma unroll
        for (int j = 0; j < 4; ++j) {
            const int id = ((od[j] - kd + Do) & (Do - 1)) >> 1;
            const int ih = ((oh[j] - kh + Ho) & (Ho - 1)) >> 1;
            const int iw = ((ow[j] - kw + Wo) & (Wo - 1)) >> 1;
            sp[j] = (id * Hi + ih) * Wi + iw;
        }
        const float* wrow = &wlds[tap * CIN * 8];
#pragma unroll 2
        for (int ci = 0; ci < CIN; ++ci) {
            float xv[4];
#pragma unroll
            for (int j = 0; j < 4; ++j)
                xv[j] = in[(size_t)ci * Vi + sp[j]];
            const float4 wa = *(const float4*)(wrow + ci * 8);
            const float4 wb = *(const float4*)(wrow + ci * 8 + 4);
#define UF(WC, CO)                                                              \
            {                                                                   \
                _Pragma("unroll")                                               \
                for (int j = 0; j < 4; ++j)                                     \
                    acc[(CO) * 4 + j] = fmaf(xv[j], (WC), acc[(CO) * 4 + j]);   \
            }
            UF(wa.x, 0) UF(wa.y, 1) UF(wa.z, 2) UF(wa.w, 3)
            UF(wb.x, 4) UF(wb.y, 5) UF(wb.z, 6) UF(wb.w, 7)
#undef UF
        }
    }
#pragma unroll
    for (int co = 0; co < 8; ++co)
#pragma unroll
        for (int j = 0; j < 4; ++j)
            out[(size_t)(co0 + co) * Vo + vbase + j * 256] = acc[co * 4 + j];

    float s1[8], s2[8];
#pragma unroll
    for (int co = 0; co < 8; ++co) {
        const float* a = &acc[co * 4];
        s1[co] = a[0] + a[1] + a[2] + a[3];
        s2[co] = fmaf(a[0], a[0], fmaf(a[1], a[1], fmaf(a[2], a[2], a[3] * a[3])));
    }
#pragma unroll
    for (int off = 32; off > 0; off >>= 1)
#pragma unroll
        for (int co = 0; co < 8; ++co) {
            s1[co] += __shfl_down(s1[co], off, 64);
            s2[co] += __shfl_down(s2[co], off, 64);
        }
    const int lane = threadIdx.x & 63;
    const int wv   = threadIdx.x >> 6;
    if (lane == 0)
#pragma unroll
        for (int co = 0; co < 8; ++co) {
            sred[(wv * 8 + co) * 2]     = s1[co];
            sred[(wv * 8 + co) * 2 + 1] = s2[co];
        }
    __syncthreads();
    if ((int)threadIdx.x < 8) {
        float S1 = 0.f, S2 = 0.f;
#pragma unroll
        for (int w = 0; w < 4; ++w) {
            S1 += sred[(w * 8 + threadIdx.x) * 2];
            S2 += sred[(w * 8 + threadIdx.x) * 2 + 1];
        }
        bstat[((size_t)(co0 + threadIdx.x) * NB + blockIdx.y) * 2]     = S1;
        bstat[((size_t)(co0 + threadIdx.x) * NB + blockIdx.y) * 2 + 1] = S2;
    }
}

// ---------------------------------------------------------------------------
// fused BN apply (bstat path): re-reduce per-block partials, normalize+lrelu.
// ---------------------------------------------------------------------------
__global__ __launch_bounds__(256) void bn_apply_f(const float* __restrict__ prt,
                                                  float* __restrict__ dst,
                                                  const float* __restrict__ bstat,
                                                  int NB, int V4, float invV) {
    const int c = blockIdx.x;
    float s1 = 0.f, s2 = 0.f;
    for (int i = threadIdx.x; i < NB; i += 256) {
        s1 += bstat[((size_t)c * NB + i) * 2];
        s2 += bstat[((size_t)c * NB + i) * 2 + 1];
    }
#pragma unroll
    for (int off = 32; off > 0; off >>= 1) {
        s1 += __shfl_down(s1, off, 64);
        s2 += __shfl_down(s2, off, 64);
    }
    __shared__ float sh[8];
    __shared__ float mv[2];
    const int lane = threadIdx.x & 63;
    const int wv   = threadIdx.x >> 6;
    if (lane == 0) { sh[wv] = s1; sh[4 + wv] = s2; }
    __syncthreads();
    if (threadIdx.x == 0) {
        const float S1 = sh[0] + sh[1] + sh[2] + sh[3];
        const float S2 = sh[4] + sh[5] + sh[6] + sh[7];
        const float mean = S1 * invV;
        const float var  = S2 * invV - mean * mean;
        mv[0] = mean;
        mv[1] = rsqrtf(var + EPS);
    }
    __syncthreads();
    const float mean = mv[0];
    const float rstd = mv[1];
    const int pos = blockIdx.y * 256 + threadIdx.x;
    float4 t = ((const float4*)prt)[(size_t)c * V4 + pos];
    float u;
    u = (t.x - mean) * rstd; t.x = u >= 0.f ? u : SLOPE * u;
    u = (t.y - mean) * rstd; t.y = u >= 0.f ? u : SLOPE * u;
    u = (t.z - mean) * rstd; t.z = u >= 0.f ? u : SLOPE * u;
    u = (t.w - mean) * rstd; t.w = u >= 0.f ? u : SLOPE * u;
    ((float4*)dst)[(size_t)c * V4 + pos] = t;
}

// ---------------------------------------------------------------------------
// conv 3x3x3 (R10-proven, 4-wide, ci-split): for 32^3 / 16^3 / 8^3 layers.
// ---------------------------------------------------------------------------
template <int CIN, int CC, int BT>
__global__ __launch_bounds__(BT) void conv3_qA(const float* __restrict__ in,
                                               const float* __restrict__ wt,
                                               float* __restrict__ part,
                                               int D, int H, int W) {
    const int V    = D * H * W;
    const int Cout = gridDim.x * 8;
    const int z    = blockIdx.z;
    const int cib  = z * CC;
    __shared__ float wlds[27 * CC * 8];
    const int co0 = blockIdx.x * 8;
    for (int i = threadIdx.x; i < 27 * CC * 8; i += BT) {
        const int co  = i & 7;
        const int t2  = i >> 3;
        const int tap = t2 % 3;
        const int t3  = t2 / 3;
        const int ci  = t3 % CC;
        const int pl  = t3 / CC;
        wlds[i] = wt[((size_t)(co0 + co) * CIN + cib + ci) * 27 + pl * 3 + tap];
    }
    __syncthreads();

    const float* inz = in + (size_t)cib * V;
    const int v0 = (blockIdx.y * BT + threadIdx.x) * 4;
    const int w0 = v0 % W;
    const int h0 = (v0 / W) % H;
    const int d0 = v0 / (W * H);

    const bool mL = (w0 != 0);
    const bool mR = (w0 + 4 != W);
    const int  wl = w0 - (mL ? 1 : 0);
    const int  wr = w0 + (mR ? 4 : 3);

    float acc[32];
#pragma unroll
    for (int i = 0; i < 32; ++i) acc[i] = 0.f;

#pragma unroll 1
    for (int kd = 0; kd < 3; ++kd) {
#pragma unroll 1
        for (int kh = 0; kh < 3; ++kh) {
            const int zd = d0 + kd - 1, zh = h0 + kh - 1;
            const bool okp = ((unsigned)zd < (unsigned)D) & ((unsigned)zh < (unsigned)H);
            const int row = okp ? (zd * H + zh) * W : 0;
            const float* wpl = &wlds[(kd * 3 + kh) * CC * 24];
#pragma unroll 2
            for (int ci = 0; ci < CC; ++ci) {
                const float* p = inz + (size_t)ci * V + row;
                float4 m = *(const float4*)(p + w0);
                float lv = p[wl];
                float rv = p[wr];
                if (!okp) { m.x = 0.f; m.y = 0.f; m.z = 0.f; m.w = 0.f; }
                if (!(okp && mL)) lv = 0.f;
                if (!(okp && mR)) rv = 0.f;
                const float* wb = wpl + ci * 24;
                const float4 t0a = *(const float4*)(wb);
                const float4 t0b = *(const float4*)(wb + 4);
                const float4 t1a = *(const float4*)(wb + 8);
                const float4 t1b = *(const float4*)(wb + 12);
                const float4 t2a = *(const float4*)(wb + 16);
                const float4 t2b = *(const float4*)(wb + 20);
#define FMA4C(A0, A1, A2, AP)                                                       \
                {                                                                   \
                    float* a = (AP);                                                \
                    a[0] = fmaf(lv,  (A0), fmaf(m.x, (A1), fmaf(m.y, (A2), a[0]))); \
                    a[1] = fmaf(m.x, (A0), fmaf(m.y, (A1), fmaf(m.z, (A2), a[1]))); \
                    a[2] = fmaf(m.y, (A0), fmaf(m.z, (A1), fmaf(m.w, (A2), a[2]))); \
                    a[3] = fmaf(m.z, (A0), fmaf(m.w, (A1), fmaf(rv,  (A2), a[3]))); \
                }
                FMA4C(t0a.x, t1a.x, t2a.x, acc + 0);
                FMA4C(t0a.y, t1a.y, t2a.y, acc + 4);
                FMA4C(t0a.z, t1a.z, t2a.z, acc + 8);
                FMA4C(t0a.w, t1a.w, t2a.w, acc + 12);
                FMA4C(t0b.x, t1b.x, t2b.x, acc + 16);
                FMA4C(t0b.y, t1b.y, t2b.y, acc + 20);
                FMA4C(t0b.z, t1b.z, t2b.z, acc + 24);
                FMA4C(t0b.w, t1b.w, t2b.w, acc + 28);
#undef FMA4C
            }
        }
    }
#pragma unroll
    for (int co = 0; co < 8; ++co)
        *(float4*)&part[((size_t)z * Cout + co0 + co) * V + v0] = *(const float4*)&acc[co * 4];
}

// ---------------------------------------------------------------------------
// upconv (R10-proven, ci-split) for up1/up2
// ---------------------------------------------------------------------------
template <int CIN, int CC, int VOXB>
__global__ __launch_bounds__(256) void upconv_v8(const float* __restrict__ in,
                                                 const float* __restrict__ wt,
                                                 float* __restrict__ part,
                                                 int Di, int Hi, int Wi) {
    const int Do = 2 * Di, Ho = 2 * Hi, Wo = 2 * Wi;
    const int Vo = Do * Ho * Wo;
    const int Vi = Di * Hi * Wi;
    const int Cout = gridDim.x * 8;
    const int z    = blockIdx.z;
    const int cib  = z * CC;
    __shared__ float wlds[8 * CC * 8];
    const int co0 = blockIdx.x * 8;
    for (int i = threadIdx.x; i < 8 * CC * 8; i += 256) {
        const int co  = i & 7;
        const int t2  = i >> 3;
        const int ci  = t2 % CC;
        const int tap = t2 / CC;
        wlds[i] = wt[((size_t)(co0 + co) * CIN + cib + ci) * 8 + tap];
    }
    __syncthreads();

    const float* inz = in + (size_t)cib * Vi;
    const int vbase = blockIdx.y * (256 * VOXB) + threadIdx.x;
    int od[VOXB], oh[VOXB], ow[VOXB];
#pragma unroll
    for (int j = 0; j < VOXB; ++j) {
        const int v = vbase + j * 256;
        ow[j] = v % Wo;
        oh[j] = (v / Wo) % Ho;
        od[j] = v / (Wo * Ho);
    }
    float acc[8 * VOXB];
#pragma unroll
    for (int i = 0; i < 8 * VOXB; ++i) acc[i] = 0.f;

#pragma unroll 1
    for (int kd = 0; kd < 2; ++kd)
#pragma unroll 1
    for (int kh = 0; kh < 2; ++kh)
#pragma unroll
    for (int kw = 0; kw < 2; ++kw) {
        const int tap = (kd * 2 + kh) * 2 + kw;
        int sp[VOXB];
#pragma unroll
        for (int j = 0; j < VOXB; ++j) {
            const int id = ((od[j] - kd + Do) & (Do - 1)) >> 1;
            const int ih = ((oh[j] - kh + Ho) & (Ho - 1)) >> 1;
            const int iw = ((ow[j] - kw + Wo) & (Wo - 1)) >> 1;
            sp[j] = (id * Hi + ih) * Wi + iw;
        }
        const float* wrow = &wlds[tap * CC * 8];
#pragma unroll 2
        for (int ci = 0; ci < CC; ++ci) {
            float xv[VOXB];
#pragma unroll
            for (int j = 0; j < VOXB; ++j)
                xv[j] = inz[(size_t)ci * Vi + sp[j]];
            const float4 wa = *(const float4*)(wrow + ci * 8);
            const float4 wb = *(const float4*)(wrow + ci * 8 + 4);
#define UF(WC, CO)                                                              \
            {                                                                   \
                _Pragma("unroll")                                               \
                for (int j = 0; j < VOXB; ++j)                                  \
                    acc[(CO) * VOXB + j] = fmaf(xv[j], (WC), acc[(CO) * VOXB + j]); \
            }
            UF(wa.x, 0) UF(wa.y, 1) UF(wa.z, 2) UF(wa.w, 3)
            UF(wb.x, 4) UF(wb.y, 5) UF(wb.z, 6) UF(wb.w, 7)
#undef UF
        }
    }
#pragma unroll
    for (int co = 0; co < 8; ++co)
#pragma unroll
        for (int j = 0; j < VOXB; ++j)
            part[((size_t)z * Cout + co0 + co) * Vo + vbase + j * 256] = acc[co * VOXB + j];
}

// ---------------------------------------------------------------------------
// split-aware BN pipeline: stats partials + (final∘apply).
// ---------------------------------------------------------------------------
__global__ __launch_bounds__(256) void bn_stats_part_v2(const float* __restrict__ part,
                                                        float* __restrict__ pstat,
                                                        int C, int V, int S, int chunk) {
    const int c = blockIdx.x, seg = blockIdx.y;
    const size_t base = (size_t)c * V + (size_t)seg * chunk;
    float s1 = 0.f, s2 = 0.f;
    for (int i = threadIdx.x * 4; i < chunk; i += 1024) {
        float4 t = make_float4(0.f, 0.f, 0.f, 0.f);
        for (int s = 0; s < S; ++s) {
            const float4 v = *(const float4*)(part + (size_t)s * C * V + base + i);
            t.x += v.x; t.y += v.y; t.z += v.z; t.w += v.w;
        }
        s1 += t.x + t.y + t.z + t.w;
        s2 = fmaf(t.x, t.x, fmaf(t.y, t.y, fmaf(t.z, t.z, fmaf(t.w, t.w, s2))));
    }
#pragma unroll
    for (int off = 32; off > 0; off >>= 1) {
        s1 += __shfl_down(s1, off, 64);
        s2 += __shfl_down(s2, off, 64);
    }
    __shared__ float sh[8];
    const int wid  = threadIdx.x >> 6;
    const int lane = threadIdx.x & 63;
    if (lane == 0) { sh[wid] = s1; sh[4 + wid] = s2; }
    __syncthreads();
    if (threadIdx.x == 0) {
        pstat[(c * gridDim.y + seg) * 2]     = sh[0] + sh[1] + sh[2] + sh[3];
        pstat[(c * gridDim.y + seg) * 2 + 1] = sh[4] + sh[5] + sh[6] + sh[7];
    }
}

__global__ __launch_bounds__(256) void bn_apply_v4(const float* __restrict__ part,
                                                   float* __restrict__ dst,
                                                   const float* __restrict__ pstat,
                                                   int C, int V4, int S, int NSEG,
                                                   float invV, int total4) {
    const int idx = blockIdx.x * blockDim.x + threadIdx.x;
    if (idx >= total4) return;
    const int c = idx / V4;
    const int v = idx - c * V4;
    float s1 = 0.f, s2 = 0.f;
    for (int g = 0; g < NSEG; ++g) {
        s1 += pstat[(c * NSEG + g) * 2];
        s2 += pstat[(c * NSEG + g) * 2 + 1];
    }
    const float mean = s1 * invV;
    const float var  = s2 * invV - mean * mean;
    const float rstd = rsqrtf(var + EPS);
    const float4* p4 = (const float4*)part;
    float4 t = make_float4(0.f, 0.f, 0.f, 0.f);
    for (int s = 0; s < S; ++s) {
        const float4 x = p4[(size_t)(s * C + c) * V4 + v];
        t.x += x.x; t.y += x.y; t.z += x.z; t.w += x.w;
    }
    float u;
    u = (t.x - mean) * rstd; t.x = u >= 0.f ? u : SLOPE * u;
    u = (t.y - mean) * rstd; t.y = u >= 0.f ? u : SLOPE * u;
    u = (t.z - mean) * rstd; t.z = u >= 0.f ? u : SLOPE * u;
    u = (t.w - mean) * rstd; t.w = u >= 0.f ? u : SLOPE * u;
    ((float4*)dst)[idx] = t;
}

// ---------------------------------------------------------------------------
// 2x2x2 maxpool stride 2
// ---------------------------------------------------------------------------
__global__ __launch_bounds__(256) void maxpool_kernel(const float* __restrict__ in,
                                                      float* __restrict__ out,
                                                      int D, int H, int W, int total) {
    const int Do = D >> 1, Ho = H >> 1, Wo = W >> 1;
    const int Vo = Do * Ho * Wo;
    const int idx = blockIdx.x * blockDim.x + threadIdx.x;
    if (idx >= total) return;
    const int c  = idx / Vo;
    const int v  = idx - c * Vo;
    const int ow = v % Wo;
    const int oh = (v / Wo) % Ho;
    const int od = v / (Wo * Ho);
    const size_t HW = (size_t)H * W;
    const float* p = in + (size_t)c * D * HW + (size_t)(2 * od) * HW + (size_t)(2 * oh) * W + 2 * ow;
    float m = p[0];
    m = fmaxf(m, p[1]);
    m = fmaxf(m, p[W]);
    m = fmaxf(m, p[W + 1]);
    m = fmaxf(m, p[HW]);
    m = fmaxf(m, p[HW + 1]);
    m = fmaxf(m, p[HW + W]);
    m = fmaxf(m, p[HW + W + 1]);
    out[idx] = m;
}

// ---------------------------------------------------------------------------
// final 1x1x1 conv + bias, float4
// ---------------------------------------------------------------------------
__global__ __launch_bounds__(256) void final_v2(const float* __restrict__ in,
                                                const float* __restrict__ w,
                                                const float* __restrict__ b,
                                                float* __restrict__ out, int C, int V4) {
    const int idx = blockIdx.x * blockDim.x + threadIdx.x;
    if (idx >= V4) return;
    const float bb = b[0];
    float4 acc = make_float4(bb, bb, bb, bb);
    for (int c = 0; c < C; ++c) {
        const float4 v = ((const float4*)in)[(size_t)c * V4 + idx];
        const float wc = w[c];
        acc.x = fmaf(v.x, wc, acc.x);
        acc.y = fmaf(v.y, wc, acc.y);
        acc.z = fmaf(v.z, wc, acc.z);
        acc.w = fmaf(v.w, wc, acc.w);
    }
    ((float4*)out)[idx] = acc;
}

// ---------------------------------------------------------------------------

extern "C" void kernel_launch(void* const* d_in, const int* in_sizes, int n_in,
                              void* d_out, int out_size, void* d_ws, size_t ws_size,
                              hipStream_t stream) {
    const float* x      = (const float*)d_in[0];
    const float* wf1    = (const float*)d_in[1];
    const float* wf2    = (const float*)d_in[2];
    const float* wd1a   = (const float*)d_in[3];
    const float* wd1b   = (const float*)d_in[4];
    const float* wd2a   = (const float*)d_in[5];
    const float* wd2b   = (const float*)d_in[6];
    const float* wd3a   = (const float*)d_in[7];
    const float* wd3b   = (const float*)d_in[8];
    const float* wt1    = (const float*)d_in[9];
    const float* wu1a   = (const float*)d_in[10];
    const float* wu1b   = (const float*)d_in[11];
    const float* wt2    = (const float*)d_in[12];
    const float* wu2a   = (const float*)d_in[13];
    const float* wu2b   = (const float*)d_in[14];
    const float* wt3    = (const float*)d_in[15];
    const float* wu3a   = (const float*)d_in[16];
    const float* wu3b   = (const float*)d_in[17];
    const float* w_fin  = (const float*)d_in[18];
    const float* b_fin  = (const float*)d_in[19];
    float* out = (float*)d_out;

    const int V0 = 64 * 64 * 64;
    const int V1 = 32 * 32 * 32;
    const int V2 = 16 * 16 * 16;
    const int V3 = 8 * 8 * 8;

    float* ws    = (float*)d_ws;
    float* cat3  = ws;                         // 32 * V0
    float* cat2  = cat3 + (size_t)32 * V0;     // 64 * V1
    float* cat1  = cat2 + (size_t)64 * V1;     // 128 * V2
    float* x4    = cat1 + (size_t)128 * V2;    // 128 * V3
    float* tA    = x4   + (size_t)128 * V3;    // 16 * V0
    float* tB    = tA   + (size_t)16 * V0;     // 16 * V0
    float* part  = tB   + (size_t)16 * V0;     // 16 * V0
    float* pstat = part + (size_t)16 * V0;     // 4096
    float* bstat = pstat + 4096;               // 16*512*2 = 16384

    auto blocks = [](int n) { return (n + 255) / 256; };

    auto bn_lrelu = [&](const float* p, float* dstp, int C, int V, int S) {
        const int NSEG = (V >= V0) ? 16 : (V == V1) ? 8 : (V == V2) ? 2 : 1;
        hipLaunchKernelGGL(bn_stats_part_v2, dim3(C, NSEG), dim3(256), 0, stream,
                           p, pstat, C, V, S, V / NSEG);
        const int total4 = C * V / 4;
        hipLaunchKernelGGL(bn_apply_v4, dim3(blocks(total4)), dim3(256), 0, stream,
                           p, dstp, pstat, C, V / 4, S, NSEG, 1.f / V, total4);
    };
    auto maxpool = [&](const float* in, float* o, int C, int D, int H, int W) {
        const int total = C * (D / 2) * (H / 2) * (W / 2);
        hipLaunchKernelGGL(maxpool_kernel, dim3(blocks(total)), dim3(256), 0, stream,
                           in, o, D, H, W, total);
    };

    // big 64^3 conv (LDS-tiled, padded, reg-prefetch), S=1, fused stats.
#define CONVBIG(CIN, in_, wt_, prt_, dst_, Cout)                                            \
    {                                                                                       \
        const int NBv = V0 / 512;                                                           \
        dim3 g((Cout) / 8, NBv);                                                            \
        hipLaunchKernelGGL((conv3_big<CIN>), g, dim3(128), 0, stream,                       \
                           in_, wt_, prt_, bstat);                                          \
        hipLaunchKernelGGL(bn_apply_f, dim3(Cout, V0 / 4 / 256), dim3(256), 0, stream,      \
                           prt_, dst_, bstat, NBv, V0 / 4, 1.f / V0);                       \
    }
#define CONVQ(CIN, CC, BT, in_, wt_, prt_, dst_, Cout, D_, H_, W_)                          \
    {                                                                                       \
        const int V_ = (D_) * (H_) * (W_);                                                  \
        const int S  = (CIN) / (CC);                                                        \
        dim3 g((Cout) / 8, V_ / (4 * (BT)), S);                                             \
        hipLaunchKernelGGL((conv3_qA<CIN, CC, BT>), g, dim3(BT), 0, stream,                 \
                           in_, wt_, prt_, D_, H_, W_);                                     \
        bn_lrelu(prt_, dst_, Cout, V_, S);                                                  \
    }
#define UPCONV(CIN, CC, VOXB, in_, wt_, prt_, dst_, Cout, Di_, Hi_, Wi_)                    \
    {                                                                                       \
        const int Vo_ = 8 * (Di_) * (Hi_) * (Wi_);                                          \
        const int S  = (CIN) / (CC);                                                        \
        dim3 g((Cout) / 8, Vo_ / (256 * (VOXB)), S);                                        \
        hipLaunchKernelGGL((upconv_v8<CIN, CC, VOXB>), g, dim3(256), 0, stream,             \
                           in_, wt_, prt_, Di_, Hi_, Wi_);                                  \
        bn_lrelu(prt_, dst_, Cout, Vo_, S);                                                 \
    }

    // ----- encoder -----
    CONVBIG(1,  x,  wf1, tA, tA,   16);
    CONVBIG(16, tA, wf2, tB, cat3, 16);
    maxpool(cat3, tA, 16, 64, 64, 64);
    CONVQ(16,  8,  64,  tA,  wd1a, part, tB,          32, 32, 32, 32);
    CONVQ(32,  8,  64,  tB,  wd1b, part, cat2,        32, 32, 32, 32);
    maxpool(cat2, tA, 32, 32, 32, 32);
    CONVQ(32,  8,  64,  tA,  wd2a, part, tB,          64, 16, 16, 16);
    CONVQ(64,  8,  64,  tB,  wd2b, part, cat1,        64, 16, 16, 16);
    maxpool(cat1, tA, 64, 16, 16, 16);
    CONVQ(64,  4,  64,  tA,  wd3a, part, tB,         128, 8, 8, 8);
    CONVQ(128, 8,  64,  tB,  wd3b, part, x4,         128, 8, 8, 8);

    // ----- decoder -----
    UPCONV(128, 16, 1, x4, wt1, part, cat1 + (size_t)64 * V2, 64, 8, 8, 8);
    CONVQ(128, 8,  64, cat1, wu1a, part, tA,          64, 16, 16, 16);
    CONVQ(64,  8,  64, tA,   wu1b, part, tB,          64, 16, 16, 16);

    UPCONV(64, 16, 1, tB, wt2, part, cat2 + (size_t)32 * V1, 32, 16, 16, 16);
    CONVQ(64, 16, 64, cat2, wu2a, part, tA,           32, 32, 32, 32);
    CONVQ(32, 8,  64, tA,   wu2b, part, tB,           32, 32, 32, 32);

    {   // up3: S=1, fused stats, in-place apply into cat3[16:32]
        float* up3dst = cat3 + (size_t)16 * V0;
        const int NBv = V0 / 1024;
        dim3 g(2, NBv);
        hipLaunchKernelGGL((upconv_big<32>), g, dim3(256), 0, stream,
                           tB, wt3, up3dst, bstat, 32, 32, 32);
        hipLaunchKernelGGL(bn_apply_f, dim3(16, V0 / 4 / 256), dim3(256), 0, stream,
                           up3dst, up3dst, bstat, NBv, V0 / 4, 1.f / V0);
    }
    CONVBIG(32, cat3, wu3a, tB,   tA, 16);
    CONVBIG(16, tA,   wu3b, cat3, tB, 16);

    // ----- final 1x1x1 conv + bias -----
    hipLaunchKernelGGL(final_v2, dim3(blocks(V0 / 4)), dim3(256), 0, stream,
                       tB, w_fin, b_fin, out, 16, V0 / 4);

#undef CONVBIG
#undef CONVQ
#undef UPCONV
}

// Round 20
// 958.520 us; speedup vs baseline: 1.1774x; 1.0060x over previous
//
#include <hip/hip_runtime.h>

#define EPS   1e-5f
#define SLOPE 0.01f

// ---------------------------------------------------------------------------
// conv 3x3x3 pad=1, ci-OUTER, S=1, COB=8, W4, fused BN-stat partials,
// LDS-tiled input (pad 68) + register prefetch pipeline (R19-proven, 136us
// @ CIN=32 64^3: prefetch ci+1 into regs during ci consume; kh unrolled,
// kd/ci unroll 1 -- R14/R17 showed deeper unroll hits the VGPR cliff).
// grid: (Cout/8, V/512), BT=128. bstat[c][blockIdx.y] = (sum,sumsq).
// ---------------------------------------------------------------------------
template <int CIN>
__global__ __launch_bounds__(128) void conv3_big(const float* __restrict__ in,
                                                 const float* __restrict__ wt,
                                                 float* __restrict__ out,
                                                 float* __restrict__ bstat) {
    const int V   = 64 * 64 * 64;
    const int NB  = gridDim.y;
    const int co0 = blockIdx.x * 8;
    __shared__ float wlds[27 * CIN * 8];
    __shared__ float tile[3][10][68];
    __shared__ float sred[2 * 16];
    for (int i = threadIdx.x; i < 27 * CIN * 8; i += 128) {
        const int co  = i & 7;
        const int r   = i >> 3;
        const int tap = r % 3;
        const int r2  = r / 3;
        const int pl  = r2 % 9;
        const int ci  = r2 / 9;
        wlds[i] = wt[((size_t)(co0 + co) * CIN + ci) * 27 + pl * 3 + tap];
    }

    const int vb    = blockIdx.y * 512;
    const int d0    = vb >> 12;
    const int hbase = (vb >> 6) & 63;
    const int hh0   = threadIdx.x >> 4;
    const int w0    = (threadIdx.x & 15) * 4;
    const int v0    = vb + (hh0 * 64) + w0;
    const bool mL = (w0 != 0);
    const bool mR = (w0 + 4 != 64);

    int  goff[4];
    int  loff[4];
    bool gok[4];
    bool act[4];
#pragma unroll
    for (int t = 0; t < 4; ++t) {
        const int idx = threadIdx.x + t * 128;
        act[t] = (idx < 480);
        const int r  = idx >> 4;
        const int wq = (idx & 15) * 4;
        const int kd = r / 10;
        const int hh = r - kd * 10;
        const int zd = d0 + kd - 1;
        const int zh = hbase + hh - 1;
        gok[t]  = act[t] & ((unsigned)zd < 64u) & ((unsigned)zh < 64u);
        goff[t] = gok[t] ? ((zd << 6) + zh) * 64 + wq : 0;
        loff[t] = (kd * 10 + hh) * 68 + wq;
    }

    float acc[32];
#pragma unroll
    for (int i = 0; i < 32; ++i) acc[i] = 0.f;

    float4 pre[4];
    {
        const float* pc = in;
#pragma unroll
        for (int t = 0; t < 4; ++t) {
            float4 val = make_float4(0.f, 0.f, 0.f, 0.f);
            if (gok[t]) val = *(const float4*)(pc + goff[t]);
            pre[t] = val;
        }
    }

#pragma unroll 1
    for (int ci = 0; ci < CIN; ++ci) {
        __syncthreads();
#pragma unroll
        for (int t = 0; t < 4; ++t)
            if (act[t]) *(float4*)&((float*)tile)[loff[t]] = pre[t];
        if (ci + 1 < CIN) {
            const float* pc = in + (size_t)(ci + 1) * V;
#pragma unroll
            for (int t = 0; t < 4; ++t) {
                float4 val = make_float4(0.f, 0.f, 0.f, 0.f);
                if (gok[t]) val = *(const float4*)(pc + goff[t]);
                pre[t] = val;
            }
        }
        __syncthreads();
#pragma unroll 1
        for (int kd = 0; kd < 3; ++kd) {
#pragma unroll
            for (int kh = 0; kh < 3; ++kh) {
                const float* trow = &tile[kd][hh0 + kh][0];
                const float4 m = *(const float4*)(trow + w0);
                const float lv = mL ? trow[w0 - 1] : 0.f;
                const float rv = mR ? trow[w0 + 4] : 0.f;
                const float* wb = &wlds[((ci * 9 + kd * 3 + kh) * 3) * 8];
                const float4 t0a = *(const float4*)(wb);
                const float4 t0b = *(const float4*)(wb + 4);
                const float4 t1a = *(const float4*)(wb + 8);
                const float4 t1b = *(const float4*)(wb + 12);
                const float4 t2a = *(const float4*)(wb + 16);
                const float4 t2b = *(const float4*)(wb + 20);
#define FMA4C(A0, A1, A2, AP)                                                       \
                {                                                                   \
                    float* a = (AP);                                                \
                    a[0] = fmaf(lv,  (A0), fmaf(m.x, (A1), fmaf(m.y, (A2), a[0]))); \
                    a[1] = fmaf(m.x, (A0), fmaf(m.y, (A1), fmaf(m.z, (A2), a[1]))); \
                    a[2] = fmaf(m.y, (A0), fmaf(m.z, (A1), fmaf(m.w, (A2), a[2]))); \
                    a[3] = fmaf(m.z, (A0), fmaf(m.w, (A1), fmaf(rv,  (A2), a[3]))); \
                }
                FMA4C(t0a.x, t1a.x, t2a.x, acc + 0);
                FMA4C(t0a.y, t1a.y, t2a.y, acc + 4);
                FMA4C(t0a.z, t1a.z, t2a.z, acc + 8);
                FMA4C(t0a.w, t1a.w, t2a.w, acc + 12);
                FMA4C(t0b.x, t1b.x, t2b.x, acc + 16);
                FMA4C(t0b.y, t1b.y, t2b.y, acc + 20);
                FMA4C(t0b.z, t1b.z, t2b.z, acc + 24);
                FMA4C(t0b.w, t1b.w, t2b.w, acc + 28);
#undef FMA4C
            }
        }
    }
#pragma unroll
    for (int co = 0; co < 8; ++co)
        *(float4*)&out[(size_t)(co0 + co) * V + v0] = *(const float4*)&acc[co * 4];

    float s1[8], s2[8];
#pragma unroll
    for (int co = 0; co < 8; ++co) {
        const float* a = &acc[co * 4];
        s1[co] = a[0] + a[1] + a[2] + a[3];
        s2[co] = fmaf(a[0], a[0], fmaf(a[1], a[1], fmaf(a[2], a[2], a[3] * a[3])));
    }
#pragma unroll
    for (int off = 32; off > 0; off >>= 1)
#pragma unroll
        for (int co = 0; co < 8; ++co) {
            s1[co] += __shfl_down(s1[co], off, 64);
            s2[co] += __shfl_down(s2[co], off, 64);
        }
    const int lane = threadIdx.x & 63;
    const int wv   = threadIdx.x >> 6;
    if (lane == 0)
#pragma unroll
        for (int co = 0; co < 8; ++co) {
            sred[(wv * 8 + co) * 2]     = s1[co];
            sred[(wv * 8 + co) * 2 + 1] = s2[co];
        }
    __syncthreads();
    if ((int)threadIdx.x < 8) {
        float S1 = 0.f, S2 = 0.f;
#pragma unroll
        for (int w = 0; w < 2; ++w) {
            S1 += sred[(w * 8 + threadIdx.x) * 2];
            S2 += sred[(w * 8 + threadIdx.x) * 2 + 1];
        }
        bstat[((size_t)(co0 + threadIdx.x) * NB + blockIdx.y) * 2]     = S1;
        bstat[((size_t)(co0 + threadIdx.x) * NB + blockIdx.y) * 2 + 1] = S2;
    }
}

// ---------------------------------------------------------------------------
// NEW: conv 3x3x3 for 32^3 layers -- R19 conv3_big recipe (LDS tile, pad to
// stride 36 = 4 mod 32, register prefetch, kh unroll only) + ci-split (grid.z)
// so the split-aware BN pipeline stays unchanged. Block = 128 thr x 4w = 16
// h-rows of one d-slice. part[z][co][v] output.
// grid: (Cout/8, V1/512 = 64, CIN/CC)
// ---------------------------------------------------------------------------
template <int CIN, int CC>
__global__ __launch_bounds__(128) void conv3_t32(const float* __restrict__ in,
                                                 const float* __restrict__ wt,
                                                 float* __restrict__ part) {
    const int V    = 32 * 32 * 32;
    const int Cout = gridDim.x * 8;
    const int z    = blockIdx.z;
    const int cib  = z * CC;
    __shared__ float wlds[27 * CC * 8];
    __shared__ float tile[3][18][36];   // stride 36 = 4 mod 32: conflict-free
    const int co0 = blockIdx.x * 8;
    for (int i = threadIdx.x; i < 27 * CC * 8; i += 128) {
        const int co  = i & 7;
        const int r   = i >> 3;
        const int tap = r % 3;
        const int r2  = r / 3;
        const int pl  = r2 % 9;
        const int ci  = r2 / 9;
        wlds[i] = wt[((size_t)(co0 + co) * CIN + cib + ci) * 27 + pl * 3 + tap];
    }

    const int vb    = blockIdx.y * 512;
    const int d0    = vb >> 10;               // /1024
    const int hbase = (vb >> 5) & 31;         // 0 or 16
    const int hh0   = threadIdx.x >> 3;       // 0..15
    const int w0    = (threadIdx.x & 7) * 4;  // 0..28
    const int v0    = vb + hh0 * 32 + w0;
    const bool mL = (w0 != 0);
    const bool mR = (w0 + 4 != 32);

    // ci-invariant staging decode: 432 float4 (3 kd x 18 h x 8 quads)
    int  goff[4];
    int  loff[4];
    bool gok[4];
    bool act[4];
#pragma unroll
    for (int t = 0; t < 4; ++t) {
        const int idx = threadIdx.x + t * 128;
        act[t] = (idx < 432);
        const int r  = idx >> 3;              // 0..53 when active
        const int wq = (idx & 7) * 4;
        const int kd = r / 18;
        const int hh = r - kd * 18;
        const int zd = d0 + kd - 1;
        const int zh = hbase + hh - 1;
        gok[t]  = act[t] & ((unsigned)zd < 32u) & ((unsigned)zh < 32u);
        goff[t] = gok[t] ? ((zd << 5) + zh) * 32 + wq : 0;
        loff[t] = act[t] ? (kd * 18 + hh) * 36 + wq : 0;
    }

    float acc[32];
#pragma unroll
    for (int i = 0; i < 32; ++i) acc[i] = 0.f;

    const float* inz = in + (size_t)cib * V;
    float4 pre[4];
#pragma unroll
    for (int t = 0; t < 4; ++t) {
        float4 val = make_float4(0.f, 0.f, 0.f, 0.f);
        if (gok[t]) val = *(const float4*)(inz + goff[t]);
        pre[t] = val;
    }

#pragma unroll 1
    for (int ci = 0; ci < CC; ++ci) {
        __syncthreads();
#pragma unroll
        for (int t = 0; t < 4; ++t)
            if (act[t]) *(float4*)&((float*)tile)[loff[t]] = pre[t];
        if (ci + 1 < CC) {
            const float* pc = inz + (size_t)(ci + 1) * V;
#pragma unroll
            for (int t = 0; t < 4; ++t) {
                float4 val = make_float4(0.f, 0.f, 0.f, 0.f);
                if (gok[t]) val = *(const float4*)(pc + goff[t]);
                pre[t] = val;
            }
        }
        __syncthreads();
#pragma unroll 1
        for (int kd = 0; kd < 3; ++kd) {
#pragma unroll
            for (int kh = 0; kh < 3; ++kh) {
                const float* trow = &tile[kd][hh0 + kh][0];
                const float4 m = *(const float4*)(trow + w0);
                const float lv = mL ? trow[w0 - 1] : 0.f;
                const float rv = mR ? trow[w0 + 4] : 0.f;
                const float* wb = &wlds[((ci * 9 + kd * 3 + kh) * 3) * 8];
                const float4 t0a = *(const float4*)(wb);
                const float4 t0b = *(const float4*)(wb + 4);
                const float4 t1a = *(const float4*)(wb + 8);
                const float4 t1b = *(const float4*)(wb + 12);
                const float4 t2a = *(const float4*)(wb + 16);
                const float4 t2b = *(const float4*)(wb + 20);
#define FMA4C(A0, A1, A2, AP)                                                       \
                {                                                                   \
                    float* a = (AP);                                                \
                    a[0] = fmaf(lv,  (A0), fmaf(m.x, (A1), fmaf(m.y, (A2), a[0]))); \
                    a[1] = fmaf(m.x, (A0), fmaf(m.y, (A1), fmaf(m.z, (A2), a[1]))); \
                    a[2] = fmaf(m.y, (A0), fmaf(m.z, (A1), fmaf(m.w, (A2), a[2]))); \
                    a[3] = fmaf(m.z, (A0), fmaf(m.w, (A1), fmaf(rv,  (A2), a[3]))); \
                }
                FMA4C(t0a.x, t1a.x, t2a.x, acc + 0);
                FMA4C(t0a.y, t1a.y, t2a.y, acc + 4);
                FMA4C(t0a.z, t1a.z, t2a.z, acc + 8);
                FMA4C(t0a.w, t1a.w, t2a.w, acc + 12);
                FMA4C(t0b.x, t1b.x, t2b.x, acc + 16);
                FMA4C(t0b.y, t1b.y, t2b.y, acc + 20);
                FMA4C(t0b.z, t1b.z, t2b.z, acc + 24);
                FMA4C(t0b.w, t1b.w, t2b.w, acc + 28);
#undef FMA4C
            }
        }
    }
#pragma unroll
    for (int co = 0; co < 8; ++co)
        *(float4*)&part[((size_t)z * Cout + co0 + co) * V + v0] = *(const float4*)&acc[co * 4];
}

// ---------------------------------------------------------------------------
// upconv, S=1, COB=8, VOXB=4, fused BN-stat partials (for up3). R11-proven.
// ---------------------------------------------------------------------------
template <int CIN>
__global__ __launch_bounds__(256) void upconv_big(const float* __restrict__ in,
                                                  const float* __restrict__ wt,
                                                  float* __restrict__ out,
                                                  float* __restrict__ bstat,
                                                  int Di, int Hi, int Wi) {
    const int Do = 2 * Di, Ho = 2 * Hi, Wo = 2 * Wi;
    const int Vo = Do * Ho * Wo;
    const int Vi = Di * Hi * Wi;
    const int NB = gridDim.y;
    const int co0 = blockIdx.x * 8;
    __shared__ float wlds[8 * CIN * 8];
    __shared__ float sred[4 * 16];
    for (int i = threadIdx.x; i < 8 * CIN * 8; i += 256) {
        const int co  = i & 7;
        const int t2  = i >> 3;
        const int ci  = t2 % CIN;
        const int tap = t2 / CIN;
        wlds[i] = wt[((size_t)(co0 + co) * CIN + ci) * 8 + tap];
    }
    __syncthreads();

    const int vbase = blockIdx.y * 1024 + threadIdx.x;
    int od[4], oh[4], ow[4];
#pragma unroll
    for (int j = 0; j < 4; ++j) {
        const int v = vbase + j * 256;
        ow[j] = v % Wo;
        oh[j] = (v / Wo) % Ho;
        od[j] = v / (Wo * Ho);
    }
    float acc[32];
#pragma unroll
    for (int i = 0; i < 32; ++i) acc[i] = 0.f;

#pragma unroll 1
    for (int kd = 0; kd < 2; ++kd)
#pragma unroll 1
    for (int kh = 0; kh < 2; ++kh)
#pragma unroll
    for (int kw = 0; kw < 2; ++kw) {
        const int tap = (kd * 2 + kh) * 2 + kw;
        int sp[4];
#pragma unroll
        for (int j = 0; j < 4; ++j) {
            const int id = ((od[j] - kd + Do) & (Do - 1)) >> 1;
            const int ih = ((oh[j] - kh + Ho) & (Ho - 1)) >> 1;
            const int iw = ((ow[j] - kw + Wo) & (Wo - 1)) >> 1;
            sp[j] = (id * Hi + ih) * Wi + iw;
        }
        const float* wrow = &wlds[tap * CIN * 8];
#pragma unroll 2
        for (int ci = 0; ci < CIN; ++ci) {
            float xv[4];
#pragma unroll
            for (int j = 0; j < 4; ++j)
                xv[j] = in[(size_t)ci * Vi + sp[j]];
            const float4 wa = *(const float4*)(wrow + ci * 8);
            const float4 wb = *(const float4*)(wrow + ci * 8 + 4);
#define UF(WC, CO)                                                              \
            {                                                                   \
                _Pragma("unroll")                                               \
                for (int j = 0; j < 4; ++j)                                     \
                    acc[(CO) * 4 + j] = fmaf(xv[j], (WC), acc[(CO) * 4 + j]);   \
            }
            UF(wa.x, 0) UF(wa.y, 1) UF(wa.z, 2) UF(wa.w, 3)
            UF(wb.x, 4) UF(wb.y, 5) UF(wb.z, 6) UF(wb.w, 7)
#undef UF
        }
    }
#pragma unroll
    for (int co = 0; co < 8; ++co)
#pragma unroll
        for (int j = 0; j < 4; ++j)
            out[(size_t)(co0 + co) * Vo + vbase + j * 256] = acc[co * 4 + j];

    float s1[8], s2[8];
#pragma unroll
    for (int co = 0; co < 8; ++co) {
        const float* a = &acc[co * 4];
        s1[co] = a[0] + a[1] + a[2] + a[3];
        s2[co] = fmaf(a[0], a[0], fmaf(a[1], a[1], fmaf(a[2], a[2], a[3] * a[3])));
    }
#pragma unroll
    for (int off = 32; off > 0; off >>= 1)
#pragma unroll
        for (int co = 0; co < 8; ++co) {
            s1[co] += __shfl_down(s1[co], off, 64);
            s2[co] += __shfl_down(s2[co], off, 64);
        }
    const int lane = threadIdx.x & 63;
    const int wv   = threadIdx.x >> 6;
    if (lane == 0)
#pragma unroll
        for (int co = 0; co < 8; ++co) {
            sred[(wv * 8 + co) * 2]     = s1[co];
            sred[(wv * 8 + co) * 2 + 1] = s2[co];
        }
    __syncthreads();
    if ((int)threadIdx.x < 8) {
        float S1 = 0.f, S2 = 0.f;
#pragma unroll
        for (int w = 0; w < 4; ++w) {
            S1 += sred[(w * 8 + threadIdx.x) * 2];
            S2 += sred[(w * 8 + threadIdx.x) * 2 + 1];
        }
        bstat[((size_t)(co0 + threadIdx.x) * NB + blockIdx.y) * 2]     = S1;
        bstat[((size_t)(co0 + threadIdx.x) * NB + blockIdx.y) * 2 + 1] = S2;
    }
}

// ---------------------------------------------------------------------------
// fused BN apply (bstat path): re-reduce per-block partials, normalize+lrelu.
// ---------------------------------------------------------------------------
__global__ __launch_bounds__(256) void bn_apply_f(const float* __restrict__ prt,
                                                  float* __restrict__ dst,
                                                  const float* __restrict__ bstat,
                                                  int NB, int V4, float invV) {
    const int c = blockIdx.x;
    float s1 = 0.f, s2 = 0.f;
    for (int i = threadIdx.x; i < NB; i += 256) {
        s1 += bstat[((size_t)c * NB + i) * 2];
        s2 += bstat[((size_t)c * NB + i) * 2 + 1];
    }
#pragma unroll
    for (int off = 32; off > 0; off >>= 1) {
        s1 += __shfl_down(s1, off, 64);
        s2 += __shfl_down(s2, off, 64);
    }
    __shared__ float sh[8];
    __shared__ float mv[2];
    const int lane = threadIdx.x & 63;
    const int wv   = threadIdx.x >> 6;
    if (lane == 0) { sh[wv] = s1; sh[4 + wv] = s2; }
    __syncthreads();
    if (threadIdx.x == 0) {
        const float S1 = sh[0] + sh[1] + sh[2] + sh[3];
        const float S2 = sh[4] + sh[5] + sh[6] + sh[7];
        const float mean = S1 * invV;
        const float var  = S2 * invV - mean * mean;
        mv[0] = mean;
        mv[1] = rsqrtf(var + EPS);
    }
    __syncthreads();
    const float mean = mv[0];
    const float rstd = mv[1];
    const int pos = blockIdx.y * 256 + threadIdx.x;
    float4 t = ((const float4*)prt)[(size_t)c * V4 + pos];
    float u;
    u = (t.x - mean) * rstd; t.x = u >= 0.f ? u : SLOPE * u;
    u = (t.y - mean) * rstd; t.y = u >= 0.f ? u : SLOPE * u;
    u = (t.z - mean) * rstd; t.z = u >= 0.f ? u : SLOPE * u;
    u = (t.w - mean) * rstd; t.w = u >= 0.f ? u : SLOPE * u;
    ((float4*)dst)[(size_t)c * V4 + pos] = t;
}

// ---------------------------------------------------------------------------
// conv 3x3x3 (R10-proven, 4-wide, ci-split): for 16^3 / 8^3 layers.
// ---------------------------------------------------------------------------
template <int CIN, int CC, int BT>
__global__ __launch_bounds__(BT) void conv3_qA(const float* __restrict__ in,
                                               const float* __restrict__ wt,
                                               float* __restrict__ part,
                                               int D, int H, int W) {
    const int V    = D * H * W;
    const int Cout = gridDim.x * 8;
    const int z    = blockIdx.z;
    const int cib  = z * CC;
    __shared__ float wlds[27 * CC * 8];
    const int co0 = blockIdx.x * 8;
    for (int i = threadIdx.x; i < 27 * CC * 8; i += BT) {
        const int co  = i & 7;
        const int t2  = i >> 3;
        const int tap = t2 % 3;
        const int t3  = t2 / 3;
        const int ci  = t3 % CC;
        const int pl  = t3 / CC;
        wlds[i] = wt[((size_t)(co0 + co) * CIN + cib + ci) * 27 + pl * 3 + tap];
    }
    __syncthreads();

    const float* inz = in + (size_t)cib * V;
    const int v0 = (blockIdx.y * BT + threadIdx.x) * 4;
    const int w0 = v0 % W;
    const int h0 = (v0 / W) % H;
    const int d0 = v0 / (W * H);

    const bool mL = (w0 != 0);
    const bool mR = (w0 + 4 != W);
    const int  wl = w0 - (mL ? 1 : 0);
    const int  wr = w0 + (mR ? 4 : 3);

    float acc[32];
#pragma unroll
    for (int i = 0; i < 32; ++i) acc[i] = 0.f;

#pragma unroll 1
    for (int kd = 0; kd < 3; ++kd) {
#pragma unroll 1
        for (int kh = 0; kh < 3; ++kh) {
            const int zd = d0 + kd - 1, zh = h0 + kh - 1;
            const bool okp = ((unsigned)zd < (unsigned)D) & ((unsigned)zh < (unsigned)H);
            const int row = okp ? (zd * H + zh) * W : 0;
            const float* wpl = &wlds[(kd * 3 + kh) * CC * 24];
#pragma unroll 2
            for (int ci = 0; ci < CC; ++ci) {
                const float* p = inz + (size_t)ci * V + row;
                float4 m = *(const float4*)(p + w0);
                float lv = p[wl];
                float rv = p[wr];
                if (!okp) { m.x = 0.f; m.y = 0.f; m.z = 0.f; m.w = 0.f; }
                if (!(okp && mL)) lv = 0.f;
                if (!(okp && mR)) rv = 0.f;
                const float* wb = wpl + ci * 24;
                const float4 t0a = *(const float4*)(wb);
                const float4 t0b = *(const float4*)(wb + 4);
                const float4 t1a = *(const float4*)(wb + 8);
                const float4 t1b = *(const float4*)(wb + 12);
                const float4 t2a = *(const float4*)(wb + 16);
                const float4 t2b = *(const float4*)(wb + 20);
#define FMA4C(A0, A1, A2, AP)                                                       \
                {                                                                   \
                    float* a = (AP);                                                \
                    a[0] = fmaf(lv,  (A0), fmaf(m.x, (A1), fmaf(m.y, (A2), a[0]))); \
                    a[1] = fmaf(m.x, (A0), fmaf(m.y, (A1), fmaf(m.z, (A2), a[1]))); \
                    a[2] = fmaf(m.y, (A0), fmaf(m.z, (A1), fmaf(m.w, (A2), a[2]))); \
                    a[3] = fmaf(m.z, (A0), fmaf(m.w, (A1), fmaf(rv,  (A2), a[3]))); \
                }
                FMA4C(t0a.x, t1a.x, t2a.x, acc + 0);
                FMA4C(t0a.y, t1a.y, t2a.y, acc + 4);
                FMA4C(t0a.z, t1a.z, t2a.z, acc + 8);
                FMA4C(t0a.w, t1a.w, t2a.w, acc + 12);
                FMA4C(t0b.x, t1b.x, t2b.x, acc + 16);
                FMA4C(t0b.y, t1b.y, t2b.y, acc + 20);
                FMA4C(t0b.z, t1b.z, t2b.z, acc + 24);
                FMA4C(t0b.w, t1b.w, t2b.w, acc + 28);
#undef FMA4C
            }
        }
    }
#pragma unroll
    for (int co = 0; co < 8; ++co)
        *(float4*)&part[((size_t)z * Cout + co0 + co) * V + v0] = *(const float4*)&acc[co * 4];
}

// ---------------------------------------------------------------------------
// upconv (R10-proven, ci-split) for up1/up2
// ---------------------------------------------------------------------------
template <int CIN, int CC, int VOXB>
__global__ __launch_bounds__(256) void upconv_v8(const float* __restrict__ in,
                                                 const float* __restrict__ wt,
                                                 float* __restrict__ part,
                                                 int Di, int Hi, int Wi) {
    const int Do = 2 * Di, Ho = 2 * Hi, Wo = 2 * Wi;
    const int Vo = Do * Ho * Wo;
    const int Vi = Di * Hi * Wi;
    const int Cout = gridDim.x * 8;
    const int z    = blockIdx.z;
    const int cib  = z * CC;
    __shared__ float wlds[8 * CC * 8];
    const int co0 = blockIdx.x * 8;
    for (int i = threadIdx.x; i < 8 * CC * 8; i += 256) {
        const int co  = i & 7;
        const int t2  = i >> 3;
        const int ci  = t2 % CC;
        const int tap = t2 / CC;
        wlds[i] = wt[((size_t)(co0 + co) * CIN + cib + ci) * 8 + tap];
    }
    __syncthreads();

    const float* inz = in + (size_t)cib * Vi;
    const int vbase = blockIdx.y * (256 * VOXB) + threadIdx.x;
    int od[VOXB], oh[VOXB], ow[VOXB];
#pragma unroll
    for (int j = 0; j < VOXB; ++j) {
        const int v = vbase + j * 256;
        ow[j] = v % Wo;
        oh[j] = (v / Wo) % Ho;
        od[j] = v / (Wo * Ho);
    }
    float acc[8 * VOXB];
#pragma unroll
    for (int i = 0; i < 8 * VOXB; ++i) acc[i] = 0.f;

#pragma unroll 1
    for (int kd = 0; kd < 2; ++kd)
#pragma unroll 1
    for (int kh = 0; kh < 2; ++kh)
#pragma unroll
    for (int kw = 0; kw < 2; ++kw) {
        const int tap = (kd * 2 + kh) * 2 + kw;
        int sp[VOXB];
#pragma unroll
        for (int j = 0; j < VOXB; ++j) {
            const int id = ((od[j] - kd + Do) & (Do - 1)) >> 1;
            const int ih = ((oh[j] - kh + Ho) & (Ho - 1)) >> 1;
            const int iw = ((ow[j] - kw + Wo) & (Wo - 1)) >> 1;
            sp[j] = (id * Hi + ih) * Wi + iw;
        }
        const float* wrow = &wlds[tap * CC * 8];
#pragma unroll 2
        for (int ci = 0; ci < CC; ++ci) {
            float xv[VOXB];
#pragma unroll
            for (int j = 0; j < VOXB; ++j)
                xv[j] = inz[(size_t)ci * Vi + sp[j]];
            const float4 wa = *(const float4*)(wrow + ci * 8);
            const float4 wb = *(const float4*)(wrow + ci * 8 + 4);
#define UF(WC, CO)                                                              \
            {                                                                   \
                _Pragma("unroll")                                               \
                for (int j = 0; j < VOXB; ++j)                                  \
                    acc[(CO) * VOXB + j] = fmaf(xv[j], (WC), acc[(CO) * VOXB + j]); \
            }
            UF(wa.x, 0) UF(wa.y, 1) UF(wa.z, 2) UF(wa.w, 3)
            UF(wb.x, 4) UF(wb.y, 5) UF(wb.z, 6) UF(wb.w, 7)
#undef UF
        }
    }
#pragma unroll
    for (int co = 0; co < 8; ++co)
#pragma unroll
        for (int j = 0; j < VOXB; ++j)
            part[((size_t)z * Cout + co0 + co) * Vo + vbase + j * 256] = acc[co * VOXB + j];
}

// ---------------------------------------------------------------------------
// split-aware BN pipeline: stats partials + (final∘apply).
// ---------------------------------------------------------------------------
__global__ __launch_bounds__(256) void bn_stats_part_v2(const float* __restrict__ part,
                                                        float* __restrict__ pstat,
                                                        int C, int V, int S, int chunk) {
    const int c = blockIdx.x, seg = blockIdx.y;
    const size_t base = (size_t)c * V + (size_t)seg * chunk;
    float s1 = 0.f, s2 = 0.f;
    for (int i = threadIdx.x * 4; i < chunk; i += 1024) {
        float4 t = make_float4(0.f, 0.f, 0.f, 0.f);
        for (int s = 0; s < S; ++s) {
            const float4 v = *(const float4*)(part + (size_t)s * C * V + base + i);
            t.x += v.x; t.y += v.y; t.z += v.z; t.w += v.w;
        }
        s1 += t.x + t.y + t.z + t.w;
        s2 = fmaf(t.x, t.x, fmaf(t.y, t.y, fmaf(t.z, t.z, fmaf(t.w, t.w, s2))));
    }
#pragma unroll
    for (int off = 32; off > 0; off >>= 1) {
        s1 += __shfl_down(s1, off, 64);
        s2 += __shfl_down(s2, off, 64);
    }
    __shared__ float sh[8];
    const int wid  = threadIdx.x >> 6;
    const int lane = threadIdx.x & 63;
    if (lane == 0) { sh[wid] = s1; sh[4 + wid] = s2; }
    __syncthreads();
    if (threadIdx.x == 0) {
        pstat[(c * gridDim.y + seg) * 2]     = sh[0] + sh[1] + sh[2] + sh[3];
        pstat[(c * gridDim.y + seg) * 2 + 1] = sh[4] + sh[5] + sh[6] + sh[7];
    }
}

__global__ __launch_bounds__(256) void bn_apply_v4(const float* __restrict__ part,
                                                   float* __restrict__ dst,
                                                   const float* __restrict__ pstat,
                                                   int C, int V4, int S, int NSEG,
                                                   float invV, int total4) {
    const int idx = blockIdx.x * blockDim.x + threadIdx.x;
    if (idx >= total4) return;
    const int c = idx / V4;
    const int v = idx - c * V4;
    float s1 = 0.f, s2 = 0.f;
    for (int g = 0; g < NSEG; ++g) {
        s1 += pstat[(c * NSEG + g) * 2];
        s2 += pstat[(c * NSEG + g) * 2 + 1];
    }
    const float mean = s1 * invV;
    const float var  = s2 * invV - mean * mean;
    const float rstd = rsqrtf(var + EPS);
    const float4* p4 = (const float4*)part;
    float4 t = make_float4(0.f, 0.f, 0.f, 0.f);
    for (int s = 0; s < S; ++s) {
        const float4 x = p4[(size_t)(s * C + c) * V4 + v];
        t.x += x.x; t.y += x.y; t.z += x.z; t.w += x.w;
    }
    float u;
    u = (t.x - mean) * rstd; t.x = u >= 0.f ? u : SLOPE * u;
    u = (t.y - mean) * rstd; t.y = u >= 0.f ? u : SLOPE * u;
    u = (t.z - mean) * rstd; t.z = u >= 0.f ? u : SLOPE * u;
    u = (t.w - mean) * rstd; t.w = u >= 0.f ? u : SLOPE * u;
    ((float4*)dst)[idx] = t;
}

// ---------------------------------------------------------------------------
// 2x2x2 maxpool stride 2
// ---------------------------------------------------------------------------
__global__ __launch_bounds__(256) void maxpool_kernel(const float* __restrict__ in,
                                                      float* __restrict__ out,
                                                      int D, int H, int W, int total) {
    const int Do = D >> 1, Ho = H >> 1, Wo = W >> 1;
    const int Vo = Do * Ho * Wo;
    const int idx = blockIdx.x * blockDim.x + threadIdx.x;
    if (idx >= total) return;
    const int c  = idx / Vo;
    const int v  = idx - c * Vo;
    const int ow = v % Wo;
    const int oh = (v / Wo) % Ho;
    const int od = v / (Wo * Ho);
    const size_t HW = (size_t)H * W;
    const float* p = in + (size_t)c * D * HW + (size_t)(2 * od) * HW + (size_t)(2 * oh) * W + 2 * ow;
    float m = p[0];
    m = fmaxf(m, p[1]);
    m = fmaxf(m, p[W]);
    m = fmaxf(m, p[W + 1]);
    m = fmaxf(m, p[HW]);
    m = fmaxf(m, p[HW + 1]);
    m = fmaxf(m, p[HW + W]);
    m = fmaxf(m, p[HW + W + 1]);
    out[idx] = m;
}

// ---------------------------------------------------------------------------
// final 1x1x1 conv + bias, float4
// ---------------------------------------------------------------------------
__global__ __launch_bounds__(256) void final_v2(const float* __restrict__ in,
                                                const float* __restrict__ w,
                                                const float* __restrict__ b,
                                                float* __restrict__ out, int C, int V4) {
    const int idx = blockIdx.x * blockDim.x + threadIdx.x;
    if (idx >= V4) return;
    const float bb = b[0];
    float4 acc = make_float4(bb, bb, bb, bb);
    for (int c = 0; c < C; ++c) {
        const float4 v = ((const float4*)in)[(size_t)c * V4 + idx];
        const float wc = w[c];
        acc.x = fmaf(v.x, wc, acc.x);
        acc.y = fmaf(v.y, wc, acc.y);
        acc.z = fmaf(v.z, wc, acc.z);
        acc.w = fmaf(v.w, wc, acc.w);
    }
    ((float4*)out)[idx] = acc;
}

// ---------------------------------------------------------------------------

extern "C" void kernel_launch(void* const* d_in, const int* in_sizes, int n_in,
                              void* d_out, int out_size, void* d_ws, size_t ws_size,
                              hipStream_t stream) {
    const float* x      = (const float*)d_in[0];
    const float* wf1    = (const float*)d_in[1];
    const float* wf2    = (const float*)d_in[2];
    const float* wd1a   = (const float*)d_in[3];
    const float* wd1b   = (const float*)d_in[4];
    const float* wd2a   = (const float*)d_in[5];
    const float* wd2b   = (const float*)d_in[6];
    const float* wd3a   = (const float*)d_in[7];
    const float* wd3b   = (const float*)d_in[8];
    const float* wt1    = (const float*)d_in[9];
    const float* wu1a   = (const float*)d_in[10];
    const float* wu1b   = (const float*)d_in[11];
    const float* wt2    = (const float*)d_in[12];
    const float* wu2a   = (const float*)d_in[13];
    const float* wu2b   = (const float*)d_in[14];
    const float* wt3    = (const float*)d_in[15];
    const float* wu3a   = (const float*)d_in[16];
    const float* wu3b   = (const float*)d_in[17];
    const float* w_fin  = (const float*)d_in[18];
    const float* b_fin  = (const float*)d_in[19];
    float* out = (float*)d_out;

    const int V0 = 64 * 64 * 64;
    const int V1 = 32 * 32 * 32;
    const int V2 = 16 * 16 * 16;
    const int V3 = 8 * 8 * 8;

    float* ws    = (float*)d_ws;
    float* cat3  = ws;                         // 32 * V0
    float* cat2  = cat3 + (size_t)32 * V0;     // 64 * V1
    float* cat1  = cat2 + (size_t)64 * V1;     // 128 * V2
    float* x4    = cat1 + (size_t)128 * V2;    // 128 * V3
    float* tA    = x4   + (size_t)128 * V3;    // 16 * V0
    float* tB    = tA   + (size_t)16 * V0;     // 16 * V0
    float* part  = tB   + (size_t)16 * V0;     // 16 * V0
    float* pstat = part + (size_t)16 * V0;     // 4096
    float* bstat = pstat + 4096;               // 16*512*2 = 16384

    auto blocks = [](int n) { return (n + 255) / 256; };

    auto bn_lrelu = [&](const float* p, float* dstp, int C, int V, int S) {
        const int NSEG = (V >= V0) ? 16 : (V == V1) ? 8 : (V == V2) ? 2 : 1;
        hipLaunchKernelGGL(bn_stats_part_v2, dim3(C, NSEG), dim3(256), 0, stream,
                           p, pstat, C, V, S, V / NSEG);
        const int total4 = C * V / 4;
        hipLaunchKernelGGL(bn_apply_v4, dim3(blocks(total4)), dim3(256), 0, stream,
                           p, dstp, pstat, C, V / 4, S, NSEG, 1.f / V, total4);
    };
    auto maxpool = [&](const float* in, float* o, int C, int D, int H, int W) {
        const int total = C * (D / 2) * (H / 2) * (W / 2);
        hipLaunchKernelGGL(maxpool_kernel, dim3(blocks(total)), dim3(256), 0, stream,
                           in, o, D, H, W, total);
    };

    // big 64^3 conv (LDS-tiled, padded, reg-prefetch), S=1, fused stats.
#define CONVBIG(CIN, in_, wt_, prt_, dst_, Cout)                                            \
    {                                                                                       \
        const int NBv = V0 / 512;                                                           \
        dim3 g((Cout) / 8, NBv);                                                            \
        hipLaunchKernelGGL((conv3_big<CIN>), g, dim3(128), 0, stream,                       \
                           in_, wt_, prt_, bstat);                                          \
        hipLaunchKernelGGL(bn_apply_f, dim3(Cout, V0 / 4 / 256), dim3(256), 0, stream,      \
                           prt_, dst_, bstat, NBv, V0 / 4, 1.f / V0);                       \
    }
    // 32^3 conv (LDS-tiled, reg-prefetch, ci-split) + split BN pipeline
#define CONVT32(CIN, CC, in_, wt_, prt_, dst_, Cout)                                        \
    {                                                                                       \
        const int S = (CIN) / (CC);                                                         \
        dim3 g((Cout) / 8, V1 / 512, S);                                                    \
        hipLaunchKernelGGL((conv3_t32<CIN, CC>), g, dim3(128), 0, stream,                   \
                           in_, wt_, prt_);                                                 \
        bn_lrelu(prt_, dst_, Cout, V1, S);                                                  \
    }
#define CONVQ(CIN, CC, BT, in_, wt_, prt_, dst_, Cout, D_, H_, W_)                          \
    {                                                                                       \
        const int V_ = (D_) * (H_) * (W_);                                                  \
        const int S  = (CIN) / (CC);                                                        \
        dim3 g((Cout) / 8, V_ / (4 * (BT)), S);                                             \
        hipLaunchKernelGGL((conv3_qA<CIN, CC, BT>), g, dim3(BT), 0, stream,                 \
                           in_, wt_, prt_, D_, H_, W_);                                     \
        bn_lrelu(prt_, dst_, Cout, V_, S);                                                  \
    }
#define UPCONV(CIN, CC, VOXB, in_, wt_, prt_, dst_, Cout, Di_, Hi_, Wi_)                    \
    {                                                                                       \
        const int Vo_ = 8 * (Di_) * (Hi_) * (Wi_);                                          \
        const int S  = (CIN) / (CC);                                                        \
        dim3 g((Cout) / 8, Vo_ / (256 * (VOXB)), S);                                        \
        hipLaunchKernelGGL((upconv_v8<CIN, CC, VOXB>), g, dim3(256), 0, stream,             \
                           in_, wt_, prt_, Di_, Hi_, Wi_);                                  \
        bn_lrelu(prt_, dst_, Cout, Vo_, S);                                                 \
    }

    // ----- encoder -----
    CONVBIG(1,  x,  wf1, tA, tA,   16);
    CONVBIG(16, tA, wf2, tB, cat3, 16);
    maxpool(cat3, tA, 16, 64, 64, 64);
    CONVT32(16,  8, tA,  wd1a, part, tB,   32);     // (4,64,2)=512
    CONVT32(32,  8, tB,  wd1b, part, cat2, 32);     // (4,64,4)=1024
    maxpool(cat2, tA, 32, 32, 32, 32);
    CONVQ(32,  8,  64,  tA,  wd2a, part, tB,          64, 16, 16, 16);
    CONVQ(64,  8,  64,  tB,  wd2b, part, cat1,        64, 16, 16, 16);
    maxpool(cat1, tA, 64, 16, 16, 16);
    CONVQ(64,  4,  64,  tA,  wd3a, part, tB,         128, 8, 8, 8);
    CONVQ(128, 8,  64,  tB,  wd3b, part, x4,         128, 8, 8, 8);

    // ----- decoder -----
    UPCONV(128, 16, 1, x4, wt1, part, cat1 + (size_t)64 * V2, 64, 8, 8, 8);
    CONVQ(128, 8,  64, cat1, wu1a, part, tA,          64, 16, 16, 16);
    CONVQ(64,  8,  64, tA,   wu1b, part, tB,          64, 16, 16, 16);

    UPCONV(64, 16, 1, tB, wt2, part, cat2 + (size_t)32 * V1, 32, 16, 16, 16);
    CONVT32(64, 16, cat2, wu2a, part, tA, 32);      // (4,64,4)=1024
    CONVT32(32, 8,  tA,   wu2b, part, tB, 32);      // (4,64,4)=1024

    {   // up3: S=1, fused stats, in-place apply into cat3[16:32]
        float* up3dst = cat3 + (size_t)16 * V0;
        const int NBv = V0 / 1024;
        dim3 g(2, NBv);
        hipLaunchKernelGGL((upconv_big<32>), g, dim3(256), 0, stream,
                           tB, wt3, up3dst, bstat, 32, 32, 32);
        hipLaunchKernelGGL(bn_apply_f, dim3(16, V0 / 4 / 256), dim3(256), 0, stream,
                           up3dst, up3dst, bstat, NBv, V0 / 4, 1.f / V0);
    }
    CONVBIG(32, cat3, wu3a, tB,   tA, 16);
    CONVBIG(16, tA,   wu3b, cat3, tB, 16);

    // ----- final 1x1x1 conv + bias -----
    hipLaunchKernelGGL(final_v2, dim3(blocks(V0 / 4)), dim3(256), 0, stream,
                       tB, w_fin, b_fin, out, 16, V0 / 4);

#undef CONVBIG
#undef CONVT32
#undef CONVQ
#undef UPCONV
}

// Round 21
// 948.724 us; speedup vs baseline: 1.1895x; 1.0103x over previous
//
#include <hip/hip_runtime.h>

#define EPS   1e-5f
#define SLOPE 0.01f

// ---------------------------------------------------------------------------
// conv 3x3x3 pad=1, ci-OUTER, S=1, COB=8, W4, fused BN-stat partials,
// LDS-tiled input + register prefetch (R19/R20-proven). NEW vs R20: weights
// are read DIRECTLY from global via wave-uniform addresses (-> s_load into
// SGPRs through the scalar cache) instead of LDS. Cycle accounting showed the
// kernel is LDS-pipe-bound (~200K of 322K cy/CU in LDS; weight b128 reads are
// ~55% of that). Scalar pipe was idle; this moves the weight stream there.
// grid: (Cout/8, V/512), BT=128. bstat[c][blockIdx.y] = (sum,sumsq).
// ---------------------------------------------------------------------------
template <int CIN>
__global__ __launch_bounds__(128) void conv3_big(const float* __restrict__ in,
                                                 const float* __restrict__ wt,
                                                 float* __restrict__ out,
                                                 float* __restrict__ bstat) {
    const int V   = 64 * 64 * 64;
    const int NB  = gridDim.y;
    const int co0 = blockIdx.x * 8;
    __shared__ float tile[3][10][68];   // stride 68: minimal bank aliasing
    __shared__ float sred[2 * 16];

    const int vb    = blockIdx.y * 512;
    const int d0    = vb >> 12;
    const int hbase = (vb >> 6) & 63;
    const int hh0   = threadIdx.x >> 4;
    const int w0    = (threadIdx.x & 15) * 4;
    const int v0    = vb + (hh0 * 64) + w0;
    const bool mL = (w0 != 0);
    const bool mR = (w0 + 4 != 64);

    int  goff[4];
    int  loff[4];
    bool gok[4];
    bool act[4];
#pragma unroll
    for (int t = 0; t < 4; ++t) {
        const int idx = threadIdx.x + t * 128;
        act[t] = (idx < 480);
        const int r  = idx >> 4;
        const int wq = (idx & 15) * 4;
        const int kd = r / 10;
        const int hh = r - kd * 10;
        const int zd = d0 + kd - 1;
        const int zh = hbase + hh - 1;
        gok[t]  = act[t] & ((unsigned)zd < 64u) & ((unsigned)zh < 64u);
        goff[t] = gok[t] ? ((zd << 6) + zh) * 64 + wq : 0;
        loff[t] = (kd * 10 + hh) * 68 + wq;
    }

    float acc[32];
#pragma unroll
    for (int i = 0; i < 32; ++i) acc[i] = 0.f;

    float4 pre[4];
    {
        const float* pc = in;
#pragma unroll
        for (int t = 0; t < 4; ++t) {
            float4 val = make_float4(0.f, 0.f, 0.f, 0.f);
            if (gok[t]) val = *(const float4*)(pc + goff[t]);
            pre[t] = val;
        }
    }

#pragma unroll 1
    for (int ci = 0; ci < CIN; ++ci) {
        __syncthreads();   // prev-ci consumers done
#pragma unroll
        for (int t = 0; t < 4; ++t)
            if (act[t]) *(float4*)&((float*)tile)[loff[t]] = pre[t];
        if (ci + 1 < CIN) {
            const float* pc = in + (size_t)(ci + 1) * V;
#pragma unroll
            for (int t = 0; t < 4; ++t) {
                float4 val = make_float4(0.f, 0.f, 0.f, 0.f);
                if (gok[t]) val = *(const float4*)(pc + goff[t]);
                pre[t] = val;
            }
        }
        __syncthreads();   // tile ready
#pragma unroll 1
        for (int kd = 0; kd < 3; ++kd) {
#pragma unroll
            for (int kh = 0; kh < 3; ++kh) {
                const float* trow = &tile[kd][hh0 + kh][0];
                const float4 m = *(const float4*)(trow + w0);
                const float lv = mL ? trow[w0 - 1] : 0.f;
                const float rv = mR ? trow[w0 + 4] : 0.f;
                // wave-uniform weight reads -> scalar loads (no LDS traffic)
                const float* wbase = wt + ((size_t)co0 * CIN + ci) * 27
                                        + (kd * 3 + kh) * 3;
#define FMA4C(A0, A1, A2, AP)                                                       \
                {                                                                   \
                    float* a = (AP);                                                \
                    a[0] = fmaf(lv,  (A0), fmaf(m.x, (A1), fmaf(m.y, (A2), a[0]))); \
                    a[1] = fmaf(m.x, (A0), fmaf(m.y, (A1), fmaf(m.z, (A2), a[1]))); \
                    a[2] = fmaf(m.y, (A0), fmaf(m.z, (A1), fmaf(m.w, (A2), a[2]))); \
                    a[3] = fmaf(m.z, (A0), fmaf(m.w, (A1), fmaf(rv,  (A2), a[3]))); \
                }
#pragma unroll
                for (int co = 0; co < 8; ++co) {
                    const float* wp = wbase + (size_t)co * (CIN * 27);
                    const float a0 = wp[0];
                    const float a1 = wp[1];
                    const float a2 = wp[2];
                    FMA4C(a0, a1, a2, acc + co * 4);
                }
#undef FMA4C
            }
        }
    }
#pragma unroll
    for (int co = 0; co < 8; ++co)
        *(float4*)&out[(size_t)(co0 + co) * V + v0] = *(const float4*)&acc[co * 4];

    // fused per-block BN stat partials (valid because S=1)
    float s1[8], s2[8];
#pragma unroll
    for (int co = 0; co < 8; ++co) {
        const float* a = &acc[co * 4];
        s1[co] = a[0] + a[1] + a[2] + a[3];
        s2[co] = fmaf(a[0], a[0], fmaf(a[1], a[1], fmaf(a[2], a[2], a[3] * a[3])));
    }
#pragma unroll
    for (int off = 32; off > 0; off >>= 1)
#pragma unroll
        for (int co = 0; co < 8; ++co) {
            s1[co] += __shfl_down(s1[co], off, 64);
            s2[co] += __shfl_down(s2[co], off, 64);
        }
    const int lane = threadIdx.x & 63;
    const int wv   = threadIdx.x >> 6;
    if (lane == 0)
#pragma unroll
        for (int co = 0; co < 8; ++co) {
            sred[(wv * 8 + co) * 2]     = s1[co];
            sred[(wv * 8 + co) * 2 + 1] = s2[co];
        }
    __syncthreads();
    if ((int)threadIdx.x < 8) {
        float S1 = 0.f, S2 = 0.f;
#pragma unroll
        for (int w = 0; w < 2; ++w) {
            S1 += sred[(w * 8 + threadIdx.x) * 2];
            S2 += sred[(w * 8 + threadIdx.x) * 2 + 1];
        }
        bstat[((size_t)(co0 + threadIdx.x) * NB + blockIdx.y) * 2]     = S1;
        bstat[((size_t)(co0 + threadIdx.x) * NB + blockIdx.y) * 2 + 1] = S2;
    }
}

// ---------------------------------------------------------------------------
// conv 3x3x3 for 32^3 layers (R20-proven: LDS tile stride 36, reg prefetch,
// ci-split). part[z][co][v] output. grid: (Cout/8, V1/512, CIN/CC)
// ---------------------------------------------------------------------------
template <int CIN, int CC>
__global__ __launch_bounds__(128) void conv3_t32(const float* __restrict__ in,
                                                 const float* __restrict__ wt,
                                                 float* __restrict__ part) {
    const int V    = 32 * 32 * 32;
    const int Cout = gridDim.x * 8;
    const int z    = blockIdx.z;
    const int cib  = z * CC;
    __shared__ float wlds[27 * CC * 8];
    __shared__ float tile[3][18][36];
    const int co0 = blockIdx.x * 8;
    for (int i = threadIdx.x; i < 27 * CC * 8; i += 128) {
        const int co  = i & 7;
        const int r   = i >> 3;
        const int tap = r % 3;
        const int r2  = r / 3;
        const int pl  = r2 % 9;
        const int ci  = r2 / 9;
        wlds[i] = wt[((size_t)(co0 + co) * CIN + cib + ci) * 27 + pl * 3 + tap];
    }

    const int vb    = blockIdx.y * 512;
    const int d0    = vb >> 10;
    const int hbase = (vb >> 5) & 31;
    const int hh0   = threadIdx.x >> 3;
    const int w0    = (threadIdx.x & 7) * 4;
    const int v0    = vb + hh0 * 32 + w0;
    const bool mL = (w0 != 0);
    const bool mR = (w0 + 4 != 32);

    int  goff[4];
    int  loff[4];
    bool gok[4];
    bool act[4];
#pragma unroll
    for (int t = 0; t < 4; ++t) {
        const int idx = threadIdx.x + t * 128;
        act[t] = (idx < 432);
        const int r  = idx >> 3;
        const int wq = (idx & 7) * 4;
        const int kd = r / 18;
        const int hh = r - kd * 18;
        const int zd = d0 + kd - 1;
        const int zh = hbase + hh - 1;
        gok[t]  = act[t] & ((unsigned)zd < 32u) & ((unsigned)zh < 32u);
        goff[t] = gok[t] ? ((zd << 5) + zh) * 32 + wq : 0;
        loff[t] = act[t] ? (kd * 18 + hh) * 36 + wq : 0;
    }

    float acc[32];
#pragma unroll
    for (int i = 0; i < 32; ++i) acc[i] = 0.f;

    const float* inz = in + (size_t)cib * V;
    float4 pre[4];
#pragma unroll
    for (int t = 0; t < 4; ++t) {
        float4 val = make_float4(0.f, 0.f, 0.f, 0.f);
        if (gok[t]) val = *(const float4*)(inz + goff[t]);
        pre[t] = val;
    }

#pragma unroll 1
    for (int ci = 0; ci < CC; ++ci) {
        __syncthreads();
#pragma unroll
        for (int t = 0; t < 4; ++t)
            if (act[t]) *(float4*)&((float*)tile)[loff[t]] = pre[t];
        if (ci + 1 < CC) {
            const float* pc = inz + (size_t)(ci + 1) * V;
#pragma unroll
            for (int t = 0; t < 4; ++t) {
                float4 val = make_float4(0.f, 0.f, 0.f, 0.f);
                if (gok[t]) val = *(const float4*)(pc + goff[t]);
                pre[t] = val;
            }
        }
        __syncthreads();
#pragma unroll 1
        for (int kd = 0; kd < 3; ++kd) {
#pragma unroll
            for (int kh = 0; kh < 3; ++kh) {
                const float* trow = &tile[kd][hh0 + kh][0];
                const float4 m = *(const float4*)(trow + w0);
                const float lv = mL ? trow[w0 - 1] : 0.f;
                const float rv = mR ? trow[w0 + 4] : 0.f;
                const float* wb = &wlds[((ci * 9 + kd * 3 + kh) * 3) * 8];
                const float4 t0a = *(const float4*)(wb);
                const float4 t0b = *(const float4*)(wb + 4);
                const float4 t1a = *(const float4*)(wb + 8);
                const float4 t1b = *(const float4*)(wb + 12);
                const float4 t2a = *(const float4*)(wb + 16);
                const float4 t2b = *(const float4*)(wb + 20);
#define FMA4C(A0, A1, A2, AP)                                                       \
                {                                                                   \
                    float* a = (AP);                                                \
                    a[0] = fmaf(lv,  (A0), fmaf(m.x, (A1), fmaf(m.y, (A2), a[0]))); \
                    a[1] = fmaf(m.x, (A0), fmaf(m.y, (A1), fmaf(m.z, (A2), a[1]))); \
                    a[2] = fmaf(m.y, (A0), fmaf(m.z, (A1), fmaf(m.w, (A2), a[2]))); \
                    a[3] = fmaf(m.z, (A0), fmaf(m.w, (A1), fmaf(rv,  (A2), a[3]))); \
                }
                FMA4C(t0a.x, t1a.x, t2a.x, acc + 0);
                FMA4C(t0a.y, t1a.y, t2a.y, acc + 4);
                FMA4C(t0a.z, t1a.z, t2a.z, acc + 8);
                FMA4C(t0a.w, t1a.w, t2a.w, acc + 12);
                FMA4C(t0b.x, t1b.x, t2b.x, acc + 16);
                FMA4C(t0b.y, t1b.y, t2b.y, acc + 20);
                FMA4C(t0b.z, t1b.z, t2b.z, acc + 24);
                FMA4C(t0b.w, t1b.w, t2b.w, acc + 28);
#undef FMA4C
            }
        }
    }
#pragma unroll
    for (int co = 0; co < 8; ++co)
        *(float4*)&part[((size_t)z * Cout + co0 + co) * V + v0] = *(const float4*)&acc[co * 4];
}

// ---------------------------------------------------------------------------
// upconv, S=1, COB=8, VOXB=4, fused BN-stat partials (for up3). R11-proven.
// ---------------------------------------------------------------------------
template <int CIN>
__global__ __launch_bounds__(256) void upconv_big(const float* __restrict__ in,
                                                  const float* __restrict__ wt,
                                                  float* __restrict__ out,
                                                  float* __restrict__ bstat,
                                                  int Di, int Hi, int Wi) {
    const int Do = 2 * Di, Ho = 2 * Hi, Wo = 2 * Wi;
    const int Vo = Do * Ho * Wo;
    const int Vi = Di * Hi * Wi;
    const int NB = gridDim.y;
    const int co0 = blockIdx.x * 8;
    __shared__ float wlds[8 * CIN * 8];
    __shared__ float sred[4 * 16];
    for (int i = threadIdx.x; i < 8 * CIN * 8; i += 256) {
        const int co  = i & 7;
        const int t2  = i >> 3;
        const int ci  = t2 % CIN;
        const int tap = t2 / CIN;
        wlds[i] = wt[((size_t)(co0 + co) * CIN + ci) * 8 + tap];
    }
    __syncthreads();

    const int vbase = blockIdx.y * 1024 + threadIdx.x;
    int od[4], oh[4], ow[4];
#pragma unroll
    for (int j = 0; j < 4; ++j) {
        const int v = vbase + j * 256;
        ow[j] = v % Wo;
        oh[j] = (v / Wo) % Ho;
        od[j] = v / (Wo * Ho);
    }
    float acc[32];
#pragma unroll
    for (int i = 0; i < 32; ++i) acc[i] = 0.f;

#pragma unroll 1
    for (int kd = 0; kd < 2; ++kd)
#pragma unroll 1
    for (int kh = 0; kh < 2; ++kh)
#pragma unroll
    for (int kw = 0; kw < 2; ++kw) {
        const int tap = (kd * 2 + kh) * 2 + kw;
        int sp[4];
#pragma unroll
        for (int j = 0; j < 4; ++j) {
            const int id = ((od[j] - kd + Do) & (Do - 1)) >> 1;
            const int ih = ((oh[j] - kh + Ho) & (Ho - 1)) >> 1;
            const int iw = ((ow[j] - kw + Wo) & (Wo - 1)) >> 1;
            sp[j] = (id * Hi + ih) * Wi + iw;
        }
        const float* wrow = &wlds[tap * CIN * 8];
#pragma unroll 2
        for (int ci = 0; ci < CIN; ++ci) {
            float xv[4];
#pragma unroll
            for (int j = 0; j < 4; ++j)
                xv[j] = in[(size_t)ci * Vi + sp[j]];
            const float4 wa = *(const float4*)(wrow + ci * 8);
            const float4 wb = *(const float4*)(wrow + ci * 8 + 4);
#define UF(WC, CO)                                                              \
            {                                                                   \
                _Pragma("unroll")                                               \
                for (int j = 0; j < 4; ++j)                                     \
                    acc[(CO) * 4 + j] = fmaf(xv[j], (WC), acc[(CO) * 4 + j]);   \
            }
            UF(wa.x, 0) UF(wa.y, 1) UF(wa.z, 2) UF(wa.w, 3)
            UF(wb.x, 4) UF(wb.y, 5) UF(wb.z, 6) UF(wb.w, 7)
#undef UF
        }
    }
#pragma unroll
    for (int co = 0; co < 8; ++co)
#pragma unroll
        for (int j = 0; j < 4; ++j)
            out[(size_t)(co0 + co) * Vo + vbase + j * 256] = acc[co * 4 + j];

    float s1[8], s2[8];
#pragma unroll
    for (int co = 0; co < 8; ++co) {
        const float* a = &acc[co * 4];
        s1[co] = a[0] + a[1] + a[2] + a[3];
        s2[co] = fmaf(a[0], a[0], fmaf(a[1], a[1], fmaf(a[2], a[2], a[3] * a[3])));
    }
#pragma unroll
    for (int off = 32; off > 0; off >>= 1)
#pragma unroll
        for (int co = 0; co < 8; ++co) {
            s1[co] += __shfl_down(s1[co], off, 64);
            s2[co] += __shfl_down(s2[co], off, 64);
        }
    const int lane = threadIdx.x & 63;
    const int wv   = threadIdx.x >> 6;
    if (lane == 0)
#pragma unroll
        for (int co = 0; co < 8; ++co) {
            sred[(wv * 8 + co) * 2]     = s1[co];
            sred[(wv * 8 + co) * 2 + 1] = s2[co];
        }
    __syncthreads();
    if ((int)threadIdx.x < 8) {
        float S1 = 0.f, S2 = 0.f;
#pragma unroll
        for (int w = 0; w < 4; ++w) {
            S1 += sred[(w * 8 + threadIdx.x) * 2];
            S2 += sred[(w * 8 + threadIdx.x) * 2 + 1];
        }
        bstat[((size_t)(co0 + threadIdx.x) * NB + blockIdx.y) * 2]     = S1;
        bstat[((size_t)(co0 + threadIdx.x) * NB + blockIdx.y) * 2 + 1] = S2;
    }
}

// ---------------------------------------------------------------------------
// fused BN apply (bstat path): re-reduce per-block partials, normalize+lrelu.
// ---------------------------------------------------------------------------
__global__ __launch_bounds__(256) void bn_apply_f(const float* __restrict__ prt,
                                                  float* __restrict__ dst,
                                                  const float* __restrict__ bstat,
                                                  int NB, int V4, float invV) {
    const int c = blockIdx.x;
    float s1 = 0.f, s2 = 0.f;
    for (int i = threadIdx.x; i < NB; i += 256) {
        s1 += bstat[((size_t)c * NB + i) * 2];
        s2 += bstat[((size_t)c * NB + i) * 2 + 1];
    }
#pragma unroll
    for (int off = 32; off > 0; off >>= 1) {
        s1 += __shfl_down(s1, off, 64);
        s2 += __shfl_down(s2, off, 64);
    }
    __shared__ float sh[8];
    __shared__ float mv[2];
    const int lane = threadIdx.x & 63;
    const int wv   = threadIdx.x >> 6;
    if (lane == 0) { sh[wv] = s1; sh[4 + wv] = s2; }
    __syncthreads();
    if (threadIdx.x == 0) {
        const float S1 = sh[0] + sh[1] + sh[2] + sh[3];
        const float S2 = sh[4] + sh[5] + sh[6] + sh[7];
        const float mean = S1 * invV;
        const float var  = S2 * invV - mean * mean;
        mv[0] = mean;
        mv[1] = rsqrtf(var + EPS);
    }
    __syncthreads();
    const float mean = mv[0];
    const float rstd = mv[1];
    const int pos = blockIdx.y * 256 + threadIdx.x;
    float4 t = ((const float4*)prt)[(size_t)c * V4 + pos];
    float u;
    u = (t.x - mean) * rstd; t.x = u >= 0.f ? u : SLOPE * u;
    u = (t.y - mean) * rstd; t.y = u >= 0.f ? u : SLOPE * u;
    u = (t.z - mean) * rstd; t.z = u >= 0.f ? u : SLOPE * u;
    u = (t.w - mean) * rstd; t.w = u >= 0.f ? u : SLOPE * u;
    ((float4*)dst)[(size_t)c * V4 + pos] = t;
}

// ---------------------------------------------------------------------------
// conv 3x3x3 (R10-proven, 4-wide, ci-split): for 16^3 / 8^3 layers.
// ---------------------------------------------------------------------------
template <int CIN, int CC, int BT>
__global__ __launch_bounds__(BT) void conv3_qA(const float* __restrict__ in,
                                               const float* __restrict__ wt,
                                               float* __restrict__ part,
                                               int D, int H, int W) {
    const int V    = D * H * W;
    const int Cout = gridDim.x * 8;
    const int z    = blockIdx.z;
    const int cib  = z * CC;
    __shared__ float wlds[27 * CC * 8];
    const int co0 = blockIdx.x * 8;
    for (int i = threadIdx.x; i < 27 * CC * 8; i += BT) {
        const int co  = i & 7;
        const int t2  = i >> 3;
        const int tap = t2 % 3;
        const int t3  = t2 / 3;
        const int ci  = t3 % CC;
        const int pl  = t3 / CC;
        wlds[i] = wt[((size_t)(co0 + co) * CIN + cib + ci) * 27 + pl * 3 + tap];
    }
    __syncthreads();

    const float* inz = in + (size_t)cib * V;
    const int v0 = (blockIdx.y * BT + threadIdx.x) * 4;
    const int w0 = v0 % W;
    const int h0 = (v0 / W) % H;
    const int d0 = v0 / (W * H);

    const bool mL = (w0 != 0);
    const bool mR = (w0 + 4 != W);
    const int  wl = w0 - (mL ? 1 : 0);
    const int  wr = w0 + (mR ? 4 : 3);

    float acc[32];
#pragma unroll
    for (int i = 0; i < 32; ++i) acc[i] = 0.f;

#pragma unroll 1
    for (int kd = 0; kd < 3; ++kd) {
#pragma unroll 1
        for (int kh = 0; kh < 3; ++kh) {
            const int zd = d0 + kd - 1, zh = h0 + kh - 1;
            const bool okp = ((unsigned)zd < (unsigned)D) & ((unsigned)zh < (unsigned)H);
            const int row = okp ? (zd * H + zh) * W : 0;
            const float* wpl = &wlds[(kd * 3 + kh) * CC * 24];
#pragma unroll 2
            for (int ci = 0; ci < CC; ++ci) {
                const float* p = inz + (size_t)ci * V + row;
                float4 m = *(const float4*)(p + w0);
                float lv = p[wl];
                float rv = p[wr];
                if (!okp) { m.x = 0.f; m.y = 0.f; m.z = 0.f; m.w = 0.f; }
                if (!(okp && mL)) lv = 0.f;
                if (!(okp && mR)) rv = 0.f;
                const float* wb = wpl + ci * 24;
                const float4 t0a = *(const float4*)(wb);
                const float4 t0b = *(const float4*)(wb + 4);
                const float4 t1a = *(const float4*)(wb + 8);
                const float4 t1b = *(const float4*)(wb + 12);
                const float4 t2a = *(const float4*)(wb + 16);
                const float4 t2b = *(const float4*)(wb + 20);
#define FMA4C(A0, A1, A2, AP)                                                       \
                {                                                                   \
                    float* a = (AP);                                                \
                    a[0] = fmaf(lv,  (A0), fmaf(m.x, (A1), fmaf(m.y, (A2), a[0]))); \
                    a[1] = fmaf(m.x, (A0), fmaf(m.y, (A1), fmaf(m.z, (A2), a[1]))); \
                    a[2] = fmaf(m.y, (A0), fmaf(m.z, (A1), fmaf(m.w, (A2), a[2]))); \
                    a[3] = fmaf(m.z, (A0), fmaf(m.w, (A1), fmaf(rv,  (A2), a[3]))); \
                }
                FMA4C(t0a.x, t1a.x, t2a.x, acc + 0);
                FMA4C(t0a.y, t1a.y, t2a.y, acc + 4);
                FMA4C(t0a.z, t1a.z, t2a.z, acc + 8);
                FMA4C(t0a.w, t1a.w, t2a.w, acc + 12);
                FMA4C(t0b.x, t1b.x, t2b.x, acc + 16);
                FMA4C(t0b.y, t1b.y, t2b.y, acc + 20);
                FMA4C(t0b.z, t1b.z, t2b.z, acc + 24);
                FMA4C(t0b.w, t1b.w, t2b.w, acc + 28);
#undef FMA4C
            }
        }
    }
#pragma unroll
    for (int co = 0; co < 8; ++co)
        *(float4*)&part[((size_t)z * Cout + co0 + co) * V + v0] = *(const float4*)&acc[co * 4];
}

// ---------------------------------------------------------------------------
// upconv (R10-proven, ci-split) for up1/up2
// ---------------------------------------------------------------------------
template <int CIN, int CC, int VOXB>
__global__ __launch_bounds__(256) void upconv_v8(const float* __restrict__ in,
                                                 const float* __restrict__ wt,
                                                 float* __restrict__ part,
                                                 int Di, int Hi, int Wi) {
    const int Do = 2 * Di, Ho = 2 * Hi, Wo = 2 * Wi;
    const int Vo = Do * Ho * Wo;
    const int Vi = Di * Hi * Wi;
    const int Cout = gridDim.x * 8;
    const int z    = blockIdx.z;
    const int cib  = z * CC;
    __shared__ float wlds[8 * CC * 8];
    const int co0 = blockIdx.x * 8;
    for (int i = threadIdx.x; i < 8 * CC * 8; i += 256) {
        const int co  = i & 7;
        const int t2  = i >> 3;
        const int ci  = t2 % CC;
        const int tap = t2 / CC;
        wlds[i] = wt[((size_t)(co0 + co) * CIN + cib + ci) * 8 + tap];
    }
    __syncthreads();

    const float* inz = in + (size_t)cib * Vi;
    const int vbase = blockIdx.y * (256 * VOXB) + threadIdx.x;
    int od[VOXB], oh[VOXB], ow[VOXB];
#pragma unroll
    for (int j = 0; j < VOXB; ++j) {
        const int v = vbase + j * 256;
        ow[j] = v % Wo;
        oh[j] = (v / Wo) % Ho;
        od[j] = v / (Wo * Ho);
    }
    float acc[8 * VOXB];
#pragma unroll
    for (int i = 0; i < 8 * VOXB; ++i) acc[i] = 0.f;

#pragma unroll 1
    for (int kd = 0; kd < 2; ++kd)
#pragma unroll 1
    for (int kh = 0; kh < 2; ++kh)
#pragma unroll
    for (int kw = 0; kw < 2; ++kw) {
        const int tap = (kd * 2 + kh) * 2 + kw;
        int sp[VOXB];
#pragma unroll
        for (int j = 0; j < VOXB; ++j) {
            const int id = ((od[j] - kd + Do) & (Do - 1)) >> 1;
            const int ih = ((oh[j] - kh + Ho) & (Ho - 1)) >> 1;
            const int iw = ((ow[j] - kw + Wo) & (Wo - 1)) >> 1;
            sp[j] = (id * Hi + ih) * Wi + iw;
        }
        const float* wrow = &wlds[tap * CC * 8];
#pragma unroll 2
        for (int ci = 0; ci < CC; ++ci) {
            float xv[VOXB];
#pragma unroll
            for (int j = 0; j < VOXB; ++j)
                xv[j] = inz[(size_t)ci * Vi + sp[j]];
            const float4 wa = *(const float4*)(wrow + ci * 8);
            const float4 wb = *(const float4*)(wrow + ci * 8 + 4);
#define UF(WC, CO)                                                              \
            {                                                                   \
                _Pragma("unroll")                                               \
                for (int j = 0; j < VOXB; ++j)                                  \
                    acc[(CO) * VOXB + j] = fmaf(xv[j], (WC), acc[(CO) * VOXB + j]); \
            }
            UF(wa.x, 0) UF(wa.y, 1) UF(wa.z, 2) UF(wa.w, 3)
            UF(wb.x, 4) UF(wb.y, 5) UF(wb.z, 6) UF(wb.w, 7)
#undef UF
        }
    }
#pragma unroll
    for (int co = 0; co < 8; ++co)
#pragma unroll
        for (int j = 0; j < VOXB; ++j)
            part[((size_t)z * Cout + co0 + co) * Vo + vbase + j * 256] = acc[co * VOXB + j];
}

// ---------------------------------------------------------------------------
// split-aware BN pipeline: stats partials + (final∘apply).
// ---------------------------------------------------------------------------
__global__ __launch_bounds__(256) void bn_stats_part_v2(const float* __restrict__ part,
                                                        float* __restrict__ pstat,
                                                        int C, int V, int S, int chunk) {
    const int c = blockIdx.x, seg = blockIdx.y;
    const size_t base = (size_t)c * V + (size_t)seg * chunk;
    float s1 = 0.f, s2 = 0.f;
    for (int i = threadIdx.x * 4; i < chunk; i += 1024) {
        float4 t = make_float4(0.f, 0.f, 0.f, 0.f);
        for (int s = 0; s < S; ++s) {
            const float4 v = *(const float4*)(part + (size_t)s * C * V + base + i);
            t.x += v.x; t.y += v.y; t.z += v.z; t.w += v.w;
        }
        s1 += t.x + t.y + t.z + t.w;
        s2 = fmaf(t.x, t.x, fmaf(t.y, t.y, fmaf(t.z, t.z, fmaf(t.w, t.w, s2))));
    }
#pragma unroll
    for (int off = 32; off > 0; off >>= 1) {
        s1 += __shfl_down(s1, off, 64);
        s2 += __shfl_down(s2, off, 64);
    }
    __shared__ float sh[8];
    const int wid  = threadIdx.x >> 6;
    const int lane = threadIdx.x & 63;
    if (lane == 0) { sh[wid] = s1; sh[4 + wid] = s2; }
    __syncthreads();
    if (threadIdx.x == 0) {
        pstat[(c * gridDim.y + seg) * 2]     = sh[0] + sh[1] + sh[2] + sh[3];
        pstat[(c * gridDim.y + seg) * 2 + 1] = sh[4] + sh[5] + sh[6] + sh[7];
    }
}

__global__ __launch_bounds__(256) void bn_apply_v4(const float* __restrict__ part,
                                                   float* __restrict__ dst,
                                                   const float* __restrict__ pstat,
                                                   int C, int V4, int S, int NSEG,
                                                   float invV, int total4) {
    const int idx = blockIdx.x * blockDim.x + threadIdx.x;
    if (idx >= total4) return;
    const int c = idx / V4;
    const int v = idx - c * V4;
    float s1 = 0.f, s2 = 0.f;
    for (int g = 0; g < NSEG; ++g) {
        s1 += pstat[(c * NSEG + g) * 2];
        s2 += pstat[(c * NSEG + g) * 2 + 1];
    }
    const float mean = s1 * invV;
    const float var  = s2 * invV - mean * mean;
    const float rstd = rsqrtf(var + EPS);
    const float4* p4 = (const float4*)part;
    float4 t = make_float4(0.f, 0.f, 0.f, 0.f);
    for (int s = 0; s < S; ++s) {
        const float4 x = p4[(size_t)(s * C + c) * V4 + v];
        t.x += x.x; t.y += x.y; t.z += x.z; t.w += x.w;
    }
    float u;
    u = (t.x - mean) * rstd; t.x = u >= 0.f ? u : SLOPE * u;
    u = (t.y - mean) * rstd; t.y = u >= 0.f ? u : SLOPE * u;
    u = (t.z - mean) * rstd; t.z = u >= 0.f ? u : SLOPE * u;
    u = (t.w - mean) * rstd; t.w = u >= 0.f ? u : SLOPE * u;
    ((float4*)dst)[idx] = t;
}

// ---------------------------------------------------------------------------
// 2x2x2 maxpool stride 2
// ---------------------------------------------------------------------------
__global__ __launch_bounds__(256) void maxpool_kernel(const float* __restrict__ in,
                                                      float* __restrict__ out,
                                                      int D, int H, int W, int total) {
    const int Do = D >> 1, Ho = H >> 1, Wo = W >> 1;
    const int Vo = Do * Ho * Wo;
    const int idx = blockIdx.x * blockDim.x + threadIdx.x;
    if (idx >= total) return;
    const int c  = idx / Vo;
    const int v  = idx - c * Vo;
    const int ow = v % Wo;
    const int oh = (v / Wo) % Ho;
    const int od = v / (Wo * Ho);
    const size_t HW = (size_t)H * W;
    const float* p = in + (size_t)c * D * HW + (size_t)(2 * od) * HW + (size_t)(2 * oh) * W + 2 * ow;
    float m = p[0];
    m = fmaxf(m, p[1]);
    m = fmaxf(m, p[W]);
    m = fmaxf(m, p[W + 1]);
    m = fmaxf(m, p[HW]);
    m = fmaxf(m, p[HW + 1]);
    m = fmaxf(m, p[HW + W]);
    m = fmaxf(m, p[HW + W + 1]);
    out[idx] = m;
}

// ---------------------------------------------------------------------------
// final 1x1x1 conv + bias, float4
// ---------------------------------------------------------------------------
__global__ __launch_bounds__(256) void final_v2(const float* __restrict__ in,
                                                const float* __restrict__ w,
                                                const float* __restrict__ b,
                                                float* __restrict__ out, int C, int V4) {
    const int idx = blockIdx.x * blockDim.x + threadIdx.x;
    if (idx >= V4) return;
    const float bb = b[0];
    float4 acc = make_float4(bb, bb, bb, bb);
    for (int c = 0; c < C; ++c) {
        const float4 v = ((const float4*)in)[(size_t)c * V4 + idx];
        const float wc = w[c];
        acc.x = fmaf(v.x, wc, acc.x);
        acc.y = fmaf(v.y, wc, acc.y);
        acc.z = fmaf(v.z, wc, acc.z);
        acc.w = fmaf(v.w, wc, acc.w);
    }
    ((float4*)out)[idx] = acc;
}

// ---------------------------------------------------------------------------

extern "C" void kernel_launch(void* const* d_in, const int* in_sizes, int n_in,
                              void* d_out, int out_size, void* d_ws, size_t ws_size,
                              hipStream_t stream) {
    const float* x      = (const float*)d_in[0];
    const float* wf1    = (const float*)d_in[1];
    const float* wf2    = (const float*)d_in[2];
    const float* wd1a   = (const float*)d_in[3];
    const float* wd1b   = (const float*)d_in[4];
    const float* wd2a   = (const float*)d_in[5];
    const float* wd2b   = (const float*)d_in[6];
    const float* wd3a   = (const float*)d_in[7];
    const float* wd3b   = (const float*)d_in[8];
    const float* wt1    = (const float*)d_in[9];
    const float* wu1a   = (const float*)d_in[10];
    const float* wu1b   = (const float*)d_in[11];
    const float* wt2    = (const float*)d_in[12];
    const float* wu2a   = (const float*)d_in[13];
    const float* wu2b   = (const float*)d_in[14];
    const float* wt3    = (const float*)d_in[15];
    const float* wu3a   = (const float*)d_in[16];
    const float* wu3b   = (const float*)d_in[17];
    const float* w_fin  = (const float*)d_in[18];
    const float* b_fin  = (const float*)d_in[19];
    float* out = (float*)d_out;

    const int V0 = 64 * 64 * 64;
    const int V1 = 32 * 32 * 32;
    const int V2 = 16 * 16 * 16;
    const int V3 = 8 * 8 * 8;

    float* ws    = (float*)d_ws;
    float* cat3  = ws;                         // 32 * V0
    float* cat2  = cat3 + (size_t)32 * V0;     // 64 * V1
    float* cat1  = cat2 + (size_t)64 * V1;     // 128 * V2
    float* x4    = cat1 + (size_t)128 * V2;    // 128 * V3
    float* tA    = x4   + (size_t)128 * V3;    // 16 * V0
    float* tB    = tA   + (size_t)16 * V0;     // 16 * V0
    float* part  = tB   + (size_t)16 * V0;     // 16 * V0
    float* pstat = part + (size_t)16 * V0;     // 4096
    float* bstat = pstat + 4096;               // 16*512*2 = 16384

    auto blocks = [](int n) { return (n + 255) / 256; };

    auto bn_lrelu = [&](const float* p, float* dstp, int C, int V, int S) {
        const int NSEG = (V >= V0) ? 16 : (V == V1) ? 8 : (V == V2) ? 2 : 1;
        hipLaunchKernelGGL(bn_stats_part_v2, dim3(C, NSEG), dim3(256), 0, stream,
                           p, pstat, C, V, S, V / NSEG);
        const int total4 = C * V / 4;
        hipLaunchKernelGGL(bn_apply_v4, dim3(blocks(total4)), dim3(256), 0, stream,
                           p, dstp, pstat, C, V / 4, S, NSEG, 1.f / V, total4);
    };
    auto maxpool = [&](const float* in, float* o, int C, int D, int H, int W) {
        const int total = C * (D / 2) * (H / 2) * (W / 2);
        hipLaunchKernelGGL(maxpool_kernel, dim3(blocks(total)), dim3(256), 0, stream,
                           in, o, D, H, W, total);
    };

    // big 64^3 conv (LDS-tiled input, scalar weights), S=1, fused stats.
#define CONVBIG(CIN, in_, wt_, prt_, dst_, Cout)                                            \
    {                                                                                       \
        const int NBv = V0 / 512;                                                           \
        dim3 g((Cout) / 8, NBv);                                                            \
        hipLaunchKernelGGL((conv3_big<CIN>), g, dim3(128), 0, stream,                       \
                           in_, wt_, prt_, bstat);                                          \
        hipLaunchKernelGGL(bn_apply_f, dim3(Cout, V0 / 4 / 256), dim3(256), 0, stream,      \
                           prt_, dst_, bstat, NBv, V0 / 4, 1.f / V0);                       \
    }
    // 32^3 conv (LDS-tiled, reg-prefetch, ci-split) + split BN pipeline
#define CONVT32(CIN, CC, in_, wt_, prt_, dst_, Cout)                                        \
    {                                                                                       \
        const int S = (CIN) / (CC);                                                         \
        dim3 g((Cout) / 8, V1 / 512, S);                                                    \
        hipLaunchKernelGGL((conv3_t32<CIN, CC>), g, dim3(128), 0, stream,                   \
                           in_, wt_, prt_);                                                 \
        bn_lrelu(prt_, dst_, Cout, V1, S);                                                  \
    }
#define CONVQ(CIN, CC, BT, in_, wt_, prt_, dst_, Cout, D_, H_, W_)                          \
    {                                                                                       \
        const int V_ = (D_) * (H_) * (W_);                                                  \
        const int S  = (CIN) / (CC);                                                        \
        dim3 g((Cout) / 8, V_ / (4 * (BT)), S);                                             \
        hipLaunchKernelGGL((conv3_qA<CIN, CC, BT>), g, dim3(BT), 0, stream,                 \
                           in_, wt_, prt_, D_, H_, W_);                                     \
        bn_lrelu(prt_, dst_, Cout, V_, S);                                                  \
    }
#define UPCONV(CIN, CC, VOXB, in_, wt_, prt_, dst_, Cout, Di_, Hi_, Wi_)                    \
    {                                                                                       \
        const int Vo_ = 8 * (Di_) * (Hi_) * (Wi_);                                          \
        const int S  = (CIN) / (CC);                                                        \
        dim3 g((Cout) / 8, Vo_ / (256 * (VOXB)), S);                                        \
        hipLaunchKernelGGL((upconv_v8<CIN, CC, VOXB>), g, dim3(256), 0, stream,             \
                           in_, wt_, prt_, Di_, Hi_, Wi_);                                  \
        bn_lrelu(prt_, dst_, Cout, Vo_, S);                                                 \
    }

    // ----- encoder -----
    CONVBIG(1,  x,  wf1, tA, tA,   16);
    CONVBIG(16, tA, wf2, tB, cat3, 16);
    maxpool(cat3, tA, 16, 64, 64, 64);
    CONVT32(16,  8, tA,  wd1a, part, tB,   32);
    CONVT32(32,  8, tB,  wd1b, part, cat2, 32);
    maxpool(cat2, tA, 32, 32, 32, 32);
    CONVQ(32,  8,  64,  tA,  wd2a, part, tB,          64, 16, 16, 16);
    CONVQ(64,  8,  64,  tB,  wd2b, part, cat1,        64, 16, 16, 16);
    maxpool(cat1, tA, 64, 16, 16, 16);
    CONVQ(64,  4,  64,  tA,  wd3a, part, tB,         128, 8, 8, 8);
    CONVQ(128, 8,  64,  tB,  wd3b, part, x4,         128, 8, 8, 8);

    // ----- decoder -----
    UPCONV(128, 16, 1, x4, wt1, part, cat1 + (size_t)64 * V2, 64, 8, 8, 8);
    CONVQ(128, 8,  64, cat1, wu1a, part, tA,          64, 16, 16, 16);
    CONVQ(64,  8,  64, tA,   wu1b, part, tB,          64, 16, 16, 16);

    UPCONV(64, 16, 1, tB, wt2, part, cat2 + (size_t)32 * V1, 32, 16, 16, 16);
    CONVT32(64, 16, cat2, wu2a, part, tA, 32);
    CONVT32(32, 8,  tA,   wu2b, part, tB, 32);

    {   // up3: S=1, fused stats, in-place apply into cat3[16:32]
        float* up3dst = cat3 + (size_t)16 * V0;
        const int NBv = V0 / 1024;
        dim3 g(2, NBv);
        hipLaunchKernelGGL((upconv_big<32>), g, dim3(256), 0, stream,
                           tB, wt3, up3dst, bstat, 32, 32, 32);
        hipLaunchKernelGGL(bn_apply_f, dim3(16, V0 / 4 / 256), dim3(256), 0, stream,
                           up3dst, up3dst, bstat, NBv, V0 / 4, 1.f / V0);
    }
    CONVBIG(32, cat3, wu3a, tB,   tA, 16);
    CONVBIG(16, tA,   wu3b, cat3, tB, 16);

    // ----- final 1x1x1 conv + bias -----
    hipLaunchKernelGGL(final_v2, dim3(blocks(V0 / 4)), dim3(256), 0, stream,
                       tB, w_fin, b_fin, out, 16, V0 / 4);

#undef CONVBIG
#undef CONVT32
#undef CONVQ
#undef UPCONV
}